// Round 19
// baseline (779.007 us; speedup 1.0000x reference)
//
#include <hip/hip_runtime.h>
#include <math.h>

#define LATENT 128

typedef __attribute__((ext_vector_type(8))) short bf16x8;
typedef __attribute__((ext_vector_type(4))) float f32x4;
typedef __attribute__((ext_vector_type(2))) float f32x2;
typedef __attribute__((ext_vector_type(2))) unsigned u32x2;
typedef __attribute__((ext_vector_type(4))) unsigned u32x4;

union U4B { uint4 u; bf16x8 v; };

template <typename T>
__device__ __forceinline__ T ntl(const T* p) { return __builtin_nontemporal_load(p); }

__device__ __forceinline__ unsigned short f2bf(float f) {
    unsigned int x = __float_as_uint(f);
    unsigned int r = (x + 0x7fffu + ((x >> 16) & 1u)) >> 16;   // RNE
    return (unsigned short)r;
}
__device__ __forceinline__ float bf2f(unsigned short h) {
    return __uint_as_float(((unsigned int)h) << 16);
}
__device__ __forceinline__ unsigned pk2(float a, float b) {
    return (unsigned)f2bf(a) | ((unsigned)f2bf(b) << 16);
}
__device__ __forceinline__ float lo16(unsigned u) { return __uint_as_float(u << 16); }
__device__ __forceinline__ float hi16(unsigned u) { return __uint_as_float(u & 0xffff0000u); }

// direct global->LDS DMA, 16B per lane (wave-uniform LDS base + lane*16)
__device__ __forceinline__ void gld16(const void* g, void* l) {
    __builtin_amdgcn_global_load_lds(
        (const __attribute__((address_space(1))) unsigned int*)g,
        (__attribute__((address_space(3))) unsigned int*)l, 16, 0, 0);
}

// ---------------- graph-id: binary search over offsets ----------------
__global__ void k_gidfill(const int* __restrict__ goff, int G, int n, int* __restrict__ gid) {
    int i = blockIdx.x * 256 + threadIdx.x;
    if (i >= n) return;
    int lo = 0, hi = G - 1;
    while (lo < hi) {
        int mid = (lo + hi + 1) >> 1;
        if (goff[mid] <= i) lo = mid; else hi = mid - 1;
    }
    gid[i] = lo;
}

// ---------------- weight pack: fp32 row-major [K][N] -> bf16 MFMA-B frags ----
#define FN  1152
#define FE3 1248
#define FEV 1280
__global__ __launch_bounds__(256) void k_pack2(const float* __restrict__ mw0,
                                               const float* __restrict__ mw1,
                                               const float* __restrict__ mw2,
                                               const float* __restrict__ w1,
                                               const float* __restrict__ w3,
                                               uint4* __restrict__ pw) {
    int tid = blockIdx.x * 256 + threadIdx.x;
    if (tid >= 1312 * 64) return;
    int fid = tid >> 6, lane = tid & 63;
    const float* src; int kt, nt, N;
    if (fid < 512)       { src = mw0;            kt = fid >> 5;           nt = fid & 31;           N = 512; }
    else if (fid < 1024) { src = mw1;            kt = (fid - 512) >> 5;   nt = (fid - 512) & 31;   N = 512; }
    else if (fid < 1152) { src = mw2;            kt = (fid - 1024) >> 3;  nt = (fid - 1024) & 7;   N = 128; }
    else if (fid < 1184) { src = w1;             kt = (fid - 1152) >> 3;  nt = (fid - 1152) & 7;   N = 128; }
    else if (fid < 1216) { src = w1 + 128 * 128; kt = (fid - 1184) >> 3;  nt = (fid - 1184) & 7;   N = 128; }
    else if (fid < 1248) { src = w3;             kt = (fid - 1216) >> 3;  nt = (fid - 1216) & 7;   N = 128; }
    else if (fid < 1280) { src = w1 + 256 * 128; kt = (fid - 1248) >> 3;  nt = (fid - 1248) & 7;   N = 128; }
    else                 { src = w3 + 128 * 128; kt = (fid - 1280) >> 3;  nt = (fid - 1280) & 7;   N = 128; }
    int col = nt * 16 + (lane & 15);
    int k0 = kt * 32 + (lane >> 4) * 8;
    unsigned int w[4];
#pragma unroll
    for (int p = 0; p < 4; ++p) {
        unsigned int lo = f2bf(src[(size_t)(k0 + 2 * p) * N + col]);
        unsigned int hi = f2bf(src[(size_t)(k0 + 2 * p + 1) * N + col]);
        w[p] = lo | (hi << 16);
    }
    pw[(size_t)fid * 64 + lane] = make_uint4(w[0], w[1], w[2], w[3]);
}

// ---------------- CSR build ----------------
__global__ void k_count(const int* __restrict__ edges, int E,
                        int* __restrict__ deg_s, int* __restrict__ deg_r) {
    int e = blockIdx.x * 256 + threadIdx.x;
    if (e < E) { atomicAdd(&deg_s[edges[e]], 1); atomicAdd(&deg_r[edges[E + e]], 1); }
}

// parallel two-level shuffle scan (1024 threads)
__global__ __launch_bounds__(1024) void k_scan(const int* __restrict__ deg, int n,
                                               int* __restrict__ rowptr, int* __restrict__ cursor) {
    __shared__ int wsum[16];
    int t = threadIdx.x;
    int chunk = (n + 1023) / 1024;
    int s = t * chunk; if (s > n) s = n;
    int epos = s + chunk; if (epos > n) epos = n;
    int sum = 0;
    for (int i = s; i < epos; ++i) sum += deg[i];
    int lane = t & 63, wid = t >> 6;
    int v = sum;
#pragma unroll
    for (int d = 1; d < 64; d <<= 1) { int o = __shfl_up(v, d); if (lane >= d) v += o; }
    if (lane == 63) wsum[wid] = v;
    __syncthreads();
    if (t < 16) {
        int wv = wsum[t];
#pragma unroll
        for (int d = 1; d < 16; d <<= 1) { int o = __shfl_up(wv, d, 16); if (t >= d) wv += o; }
        wsum[t] = wv;
    }
    __syncthreads();
    int woff = wid ? wsum[wid - 1] : 0;
    int run = v + woff - sum;   // exclusive prefix of this thread's chunk
    for (int i = s; i < epos; ++i) { rowptr[i] = run; if (cursor) cursor[i] = run; run += deg[i]; }
    if (t == 1023) rowptr[n] = run;
}

// fill: inverse slot maps only
__global__ void k_fill(const int* __restrict__ edges, int E,
                       int* __restrict__ cur_s, int* __restrict__ cur_r,
                       int* __restrict__ sm_s, int* __restrict__ sm_r) {
    int e = blockIdx.x * 256 + threadIdx.x;
    if (e < E) {
        int r = edges[e], c = edges[E + e];
        sm_s[e] = atomicAdd(&cur_s[r], 1);
        sm_r[e] = atomicAdd(&cur_r[c], 1);
    }
}

// ---------------- node projections (MFMA): PQK=[nf@W1q | nf@W1k], PV=nf@W3k (bf16)
__global__ __launch_bounds__(512) void k_nodepre2(const float* __restrict__ nf, int n,
                                                  const uint4* __restrict__ pw,
                                                  unsigned short* __restrict__ PQK,
                                                  unsigned short* __restrict__ PVh) {
    __shared__ uint4 xs[32 * 64];   // 32KB, A-frags: [kt4][rtile8][lane64]
    int t = threadIdx.x, lane = t & 63, w = t >> 6;
    int wr = w >> 2, wc = w & 3, l15 = lane & 15, lg = lane >> 4;
    int base = blockIdx.x * 128;
#pragma unroll
    for (int it = 0; it < 4; ++it) {
        int chunk = t + it * 512;
        int row = chunk >> 4, k8 = chunk & 15, k = k8 * 8;
        int node = base + row;
        f32x4 v0 = (f32x4)(0.f), v1 = (f32x4)(0.f);
        if (node < n) {
            const f32x4* s4 = (const f32x4*)(nf + (size_t)node * 128 + k);
            v0 = ntl(s4); v1 = ntl(s4 + 1);
        }
        uint4 pkv;
        pkv.x = pk2(v0.x, v0.y); pkv.y = pk2(v0.z, v0.w);
        pkv.z = pk2(v1.x, v1.y); pkv.w = pk2(v1.z, v1.w);
        int kt = k >> 5, g = (k >> 3) & 3;
        xs[(kt * 8 + (row >> 4)) * 64 + g * 16 + (row & 15)] = pkv;
    }
    __syncthreads();
    f32x4 acc[4][6];
#pragma unroll
    for (int rt = 0; rt < 4; ++rt)
#pragma unroll
        for (int ct = 0; ct < 6; ++ct) acc[rt][ct] = (f32x4)(0.f);
    for (int kt = 0; kt < 4; ++kt) {
        U4B a[4];
#pragma unroll
        for (int rt = 0; rt < 4; ++rt) a[rt].u = xs[(kt * 8 + wr * 4 + rt) * 64 + lane];
        U4B b[6];
#pragma unroll
        for (int ct = 0; ct < 6; ++ct) {
            int nt = wc * 6 + ct;
            int mat = nt >> 3, ntm = nt & 7;
            b[ct].u = pw[(size_t)(FN + mat * 32 + kt * 8 + ntm) * 64 + lane];
        }
#pragma unroll
        for (int rt = 0; rt < 4; ++rt)
#pragma unroll
            for (int ct = 0; ct < 6; ++ct)
                acc[rt][ct] = __builtin_amdgcn_mfma_f32_16x16x32_bf16(a[rt].v, b[ct].v, acc[rt][ct], 0, 0, 0);
    }
#pragma unroll
    for (int rt = 0; rt < 4; ++rt)
#pragma unroll
        for (int ct = 0; ct < 6; ++ct) {
            int nt = wc * 6 + ct;
#pragma unroll
            for (int reg = 0; reg < 4; ++reg) {
                int node = base + (wr * 4 + rt) * 16 + lg * 4 + reg;
                if (node < n) {
                    unsigned short hv = f2bf(acc[rt][ct][reg]);
                    if (nt < 16) PQK[(size_t)node * 256 + nt * 16 + l15] = hv;
                    else         PVh[(size_t)node * 128 + (nt - 16) * 16 + l15] = hv;
                }
            }
        }
}

// ---------------- edge projection (MFMA) + fused logits/exp; V = (EV+b3)+PV[other]
// LDS: 32KB -- xs (16KB, dead after MFMA) aliased by edata(=E3+b1); evdata(=EV+b3) 16KB.
// edata/evdata rows XOR-swizzled: byte ^= (e_loc&7)<<4
__global__ __launch_bounds__(256) void k_eproj1(const int* __restrict__ edges,
                                                const float* __restrict__ ea, int E,
                                                const uint4* __restrict__ pw,
                                                const unsigned short* __restrict__ PQK,
                                                const unsigned short* __restrict__ PVh,
                                                const float* __restrict__ b1,
                                                const float* __restrict__ w2,
                                                const float* __restrict__ b3,
                                                const int* __restrict__ sm_s,
                                                const int* __restrict__ sm_r,
                                                unsigned short* __restrict__ Vs,
                                                unsigned short* __restrict__ Vr,
                                                float* __restrict__ ess2, float* __restrict__ ers2) {
    __shared__ char lds[32768];
    uint4* xs = (uint4*)lds;          // 16KB A-frags, dead after MFMA loop
    char* ldsE = lds;                 // edata rows (aliases xs): E3 + b1
    char* ldsV = lds + 16384;         // evdata rows: EV + b3
    int t = threadIdx.x, lane = t & 63, w = t >> 6;
    int wc = w, l15 = lane & 15, lg = lane >> 4;
    int base = blockIdx.x * 64;
#pragma unroll
    for (int it = 0; it < 4; ++it) {
        int chunk = t + it * 256;
        int row = chunk >> 4, k8 = chunk & 15, k = k8 * 8;
        int e = base + row;
        f32x4 v0 = (f32x4)(0.f), v1 = (f32x4)(0.f);
        if (e < E) {
            const f32x4* s4 = (const f32x4*)(ea + (size_t)e * 128 + k);
            v0 = ntl(s4); v1 = ntl(s4 + 1);
        }
        uint4 pkv;
        pkv.x = pk2(v0.x, v0.y); pkv.y = pk2(v0.z, v0.w);
        pkv.z = pk2(v1.x, v1.y); pkv.w = pk2(v1.z, v1.w);
        int kt = k >> 5, g = (k >> 3) & 3;
        xs[(kt * 4 + (row >> 4)) * 64 + g * 16 + (row & 15)] = pkv;
    }
    __syncthreads();
    f32x4 acc[4][4];   // [rt][ct]: ct 0,1 = E3 cols, ct 2,3 = EV cols
#pragma unroll
    for (int rt = 0; rt < 4; ++rt)
#pragma unroll
        for (int ct = 0; ct < 4; ++ct) acc[rt][ct] = (f32x4)(0.f);
    for (int kt = 0; kt < 4; ++kt) {
        U4B a[4];
#pragma unroll
        for (int rt = 0; rt < 4; ++rt) a[rt].u = xs[(kt * 4 + rt) * 64 + lane];
        U4B b[4];
        b[0].u = pw[(size_t)(FE3 + kt * 8 + wc * 2 + 0) * 64 + lane];
        b[1].u = pw[(size_t)(FE3 + kt * 8 + wc * 2 + 1) * 64 + lane];
        b[2].u = pw[(size_t)(FEV + kt * 8 + wc * 2 + 0) * 64 + lane];
        b[3].u = pw[(size_t)(FEV + kt * 8 + wc * 2 + 1) * 64 + lane];
#pragma unroll
        for (int rt = 0; rt < 4; ++rt)
#pragma unroll
            for (int ct = 0; ct < 4; ++ct)
                acc[rt][ct] = __builtin_amdgcn_mfma_f32_16x16x32_bf16(a[rt].v, b[ct].v, acc[rt][ct], 0, 0, 0);
    }
    __syncthreads();   // xs reads complete; safe to overwrite with edata
    // E3+b1 -> ldsE (aliased), EV+b3 -> ldsV; swizzled rows
#pragma unroll
    for (int rt = 0; rt < 4; ++rt)
#pragma unroll
        for (int cc = 0; cc < 2; ++cc) {
            int col = (wc * 2 + cc) * 16 + l15;
            float b1c = b1[col], b3c = b3[col];
#pragma unroll
            for (int reg = 0; reg < 4; ++reg) {
                int e_loc = rt * 16 + lg * 4 + reg;
                int off = (e_loc * 256 + col * 2) ^ ((e_loc & 7) << 4);
                *(unsigned short*)(ldsE + off) = f2bf(acc[rt][cc][reg] + b1c);
                *(unsigned short*)(ldsV + off) = f2bf(acc[rt][2 + cc][reg] + b3c);
            }
        }
    __syncthreads();
    // scatter V = (EV+b3) + PV[other] to both slot orders (256B rows, 16 lanes x 16B)
    {
        int e4 = lane >> 4, piece = lane & 15;
#pragma unroll
        for (int i = 0; i < 4; ++i) {
            int e_loc = w * 16 + i * 4 + e4;
            int e = base + e_loc;
            if (e < E) {
                int r = edges[e], c = edges[E + e];
                int off = (e_loc * 256 + piece * 16) ^ ((e_loc & 7) << 4);
                u32x4 vev = *(const u32x4*)(ldsV + off);
                u32x4 pvc = *(const u32x4*)(PVh + (size_t)c * 128 + piece * 8);
                u32x4 pvr = *(const u32x4*)(PVh + (size_t)r * 128 + piece * 8);
                u32x4 vs, vr;
#pragma unroll
                for (int q = 0; q < 4; ++q) {
                    float e0 = lo16(vev[q]);
                    float e1 = hi16(vev[q]);
                    vs[q] = pk2(e0 + lo16(pvc[q]), e1 + hi16(pvc[q]));
                    vr[q] = pk2(e0 + lo16(pvr[q]), e1 + hi16(pvr[q]));
                }
                __builtin_nontemporal_store(vs, (u32x4*)(Vs + (size_t)sm_s[e] * 128 + piece * 8));
                __builtin_nontemporal_store(vr, (u32x4*)(Vr + (size_t)sm_r[e] * 128 + piece * 8));
            }
        }
    }
    int esub = lane >> 3, dg = lane & 7;
    float w2r[16];
    {
        const float4* w4 = (const float4*)(w2 + (dg >> 2) * 64 + (dg & 3) * 16);
#pragma unroll
        for (int q = 0; q < 4; ++q) {
            float4 wv = w4[q];
            w2r[q * 4 + 0] = wv.x; w2r[q * 4 + 1] = wv.y; w2r[q * 4 + 2] = wv.z; w2r[q * 4 + 3] = wv.w;
        }
    }
#pragma unroll
    for (int it = 0; it < 2; ++it) {
        int e_loc = w * 16 + it * 8 + esub;
        int e = base + e_loc;
        if (e >= E) break;
        int r = edges[e], c = edges[E + e];
        const uint4* Aqr = (const uint4*)(PQK + ((size_t)r << 8) + dg * 16);
        const uint4* Akc = (const uint4*)(PQK + ((size_t)c << 8) + 128 + dg * 16);
        const uint4* Aqc = (const uint4*)(PQK + ((size_t)c << 8) + dg * 16);
        const uint4* Akr = (const uint4*)(PQK + ((size_t)r << 8) + 128 + dg * 16);
        float ps = 0.f, pr = 0.f;
#pragma unroll
        for (int half = 0; half < 2; ++half) {
            int off3 = (e_loc * 256 + dg * 32 + half * 16) ^ ((e_loc & 7) << 4);
            uint4 ue3 = *(const uint4*)(ldsE + off3);
            uint4 uqr = Aqr[half], ukc = Akc[half], uqc = Aqc[half], ukr = Akr[half];
            unsigned wqr[4] = {uqr.x, uqr.y, uqr.z, uqr.w};
            unsigned wkc[4] = {ukc.x, ukc.y, ukc.z, ukc.w};
            unsigned wqc[4] = {uqc.x, uqc.y, uqc.z, uqc.w};
            unsigned wkr[4] = {ukr.x, ukr.y, ukr.z, ukr.w};
            unsigned we3[4] = {ue3.x, ue3.y, ue3.z, ue3.w};
#pragma unroll
            for (int q = 0; q < 4; ++q) {
#pragma unroll
                for (int hl = 0; hl < 2; ++hl) {
                    int i = half * 8 + q * 2 + hl;
                    float fqr = hl ? hi16(wqr[q]) : lo16(wqr[q]);
                    float fkc = hl ? hi16(wkc[q]) : lo16(wkc[q]);
                    float fqc = hl ? hi16(wqc[q]) : lo16(wqc[q]);
                    float fkr = hl ? hi16(wkr[q]) : lo16(wkr[q]);
                    float com = hl ? hi16(we3[q]) : lo16(we3[q]);   // e3 + b1 prefolded
                    float hs = fqr + fkc + com; hs = hs > 0.f ? hs : 0.2f * hs;
                    float hr = fqc + fkr + com; hr = hr > 0.f ? hr : 0.2f * hr;
                    ps += hs * w2r[i]; pr += hr * w2r[i];
                }
            }
        }
        ps += __shfl_xor(ps, 1); ps += __shfl_xor(ps, 2);
        pr += __shfl_xor(pr, 1); pr += __shfl_xor(pr, 2);
        float Es = expf(ps), Er = expf(pr);
        if (dg == 0) {
            __builtin_nontemporal_store(Es, &ess2[(size_t)sm_s[e] * 2]);
            __builtin_nontemporal_store(Er, &ers2[(size_t)sm_r[e] * 2]);
        } else if (dg == 4) {
            __builtin_nontemporal_store(Es, &ess2[(size_t)sm_s[e] * 2 + 1]);
            __builtin_nontemporal_store(Er, &ers2[(size_t)sm_r[e] * 2 + 1]);
        }
    }
}

// ---------------- per-node aggregate: fully slot-sequential streaming ----
__global__ __launch_bounds__(256) void k_aggr(int n,
                                              const int* __restrict__ rps, const int* __restrict__ rpr,
                                              const float* __restrict__ ess2, const float* __restrict__ ers2,
                                              const unsigned short* __restrict__ Vs,
                                              const unsigned short* __restrict__ Vr,
                                              unsigned short* __restrict__ out_sh,
                                              unsigned short* __restrict__ out_rh) {
    int w = threadIdx.x >> 6, lane = threadIdx.x & 63;
    int unit = blockIdx.x * 4 + w;
    if (unit >= 2 * n) return;
    bool sent = unit < n;
    int node = sent ? unit : unit - n;
    const int*      rp = sent ? rps : rpr;
    const float*    ex = sent ? ess2 : ers2;
    const unsigned* V  = (const unsigned*)(sent ? Vs : Vr);
    int s0 = rp[node], s1 = rp[node + 1];
    float z0 = 0.f, z1 = 0.f, acca = 0.f, accb = 0.f;
    int j = s0;
    for (; j + 4 <= s1; j += 4) {
        f32x2 ez[4]; unsigned v[4];
#pragma unroll
        for (int q = 0; q < 4; ++q) ez[q] = ntl((const f32x2*)(ex + 2 * (j + q)));
#pragma unroll
        for (int q = 0; q < 4; ++q) v[q] = ntl(V + (size_t)(j + q) * 64 + lane);
#pragma unroll
        for (int q = 0; q < 4; ++q) {
            z0 += ez[q].x; z1 += ez[q].y;
            float aw = (lane < 32) ? ez[q].x : ez[q].y;
            acca += aw * lo16(v[q]); accb += aw * hi16(v[q]);
        }
    }
    for (; j < s1; ++j) {
        f32x2 ez = ntl((const f32x2*)(ex + 2 * j));
        unsigned v = ntl(V + (size_t)j * 64 + lane);
        z0 += ez.x; z1 += ez.y;
        float aw = (lane < 32) ? ez.x : ez.y;
        acca += aw * lo16(v); accb += aw * hi16(v);
    }
    float zz = (lane < 32) ? z0 : z1;
    float rz = 1.f / (zz + 1e-16f);
    unsigned o = pk2(acca * rz, accb * rz);
    unsigned* outp = (unsigned*)(sent ? out_sh : out_rh);
    outp[(size_t)node * 64 + lane] = o;
}

// ---------------- fused MFMA MLP v12: 32-row tile, 8 waves, 2 blocks/CU, 32-AGPR acc ----
__global__ __launch_bounds__(512, 4) void k_mlp12(
    const float* __restrict__ nf, const unsigned short* __restrict__ out_sh,
    const unsigned short* __restrict__ out_rh,
    const float* __restrict__ u, const int* __restrict__ gid, int n,
    const uint4* __restrict__ pw,
    const float* __restrict__ mb0, const float* __restrict__ ls0, const float* __restrict__ lb0,
    const float* __restrict__ mb1, const float* __restrict__ ls1, const float* __restrict__ lb1,
    const float* __restrict__ mb2, float* __restrict__ out) {
    extern __shared__ char smem[];
    char* hx = smem;                           // 32 KB
    char* bb = smem + 32768;                   // 32 KB
    float2* red = (float2*)(smem + 65536);     // [32][4]

    int t = threadIdx.x, lane = t & 63, w = t >> 6;   // 8 waves: 2 row x 4 col
    int wr = w >> 2, wc = w & 3, l15 = lane & 15, lg = lane >> 4;
    int base = blockIdx.x * 32;

    auto stage32 = [&](int fragbase) {
        const uint4* src = pw + (size_t)fragbase * 64;
#pragma unroll
        for (int q = 0; q < 4; ++q)
            gld16(src + q * 512 + t, bb + ((size_t)q * 512 + t) * 16);
    };
    auto stage8 = [&](int fragbase) {
        const uint4* src = pw + (size_t)fragbase * 64;
        gld16(src + t, bb + (size_t)t * 16);
    };

    stage32(0);
#pragma unroll
    for (int it = 0; it < 8; ++it) {
        int chunk = t + it * 512;
        int row = chunk >> 7, kq = chunk & 127;
        int k = kq * 4;
        int node = base + row;
        u32x2 p = (u32x2)(0u);
        if (node < n) {
            int kk = k & 127;
            if (k < 128) {
                f32x4 v = ntl((const f32x4*)(nf + (size_t)node * 128 + kk));
                p.x = pk2(v.x, v.y); p.y = pk2(v.z, v.w);
            } else if (k < 384) {
                const unsigned short* s = (k < 256 ? out_sh : out_rh) + (size_t)node * 128 + kk;
                p = ntl((const u32x2*)s);
            } else {
                f32x4 v = *(const f32x4*)(u + (size_t)gid[node] * 128 + kk);
                p.x = pk2(v.x, v.y); p.y = pk2(v.z, v.w);
            }
        }
        int addr = (row * 1024 + k * 2) ^ ((row & 7) << 4);
        *(u32x2*)(hx + addr) = p;
    }
    __syncthreads();

    f32x4 acc[8];
#pragma unroll
    for (int layer = 0; layer < 2; ++layer) {
        const float* MB = layer ? mb1 : mb0;
        const float* LS = layer ? ls1 : ls0;
        const float* LB = layer ? lb1 : lb0;
        const int fbase = layer ? 512 : 0;
#pragma unroll
        for (int ct = 0; ct < 8; ++ct) acc[ct] = (f32x4)(0.f);

        for (int kt = 0; kt < 16; ++kt) {
            U4B b[8];
#pragma unroll
            for (int ct = 0; ct < 8; ++ct)
                b[ct].u = *(const uint4*)(bb + (((size_t)wc * 8 + ct) * 64 + lane) * 16);
            U4B a;
            {
                int row = wr * 16 + l15;
                int addr = (row * 1024 + kt * 64 + lg * 16) ^ ((row & 7) << 4);
                a.u = *(const uint4*)(hx + addr);
            }
            __syncthreads();
            if (kt < 15)            stage32(fbase + (kt + 1) * 32);
            else if (layer == 0)    stage32(512);
            else                    stage8(1024);
            __builtin_amdgcn_s_setprio(1);
#pragma unroll
            for (int ct = 0; ct < 8; ++ct)
                acc[ct] = __builtin_amdgcn_mfma_f32_16x16x32_bf16(a.v, b[ct].v, acc[ct], 0, 0, 0);
            __builtin_amdgcn_s_setprio(0);
            __syncthreads();
        }

        float mbv[8], lsv[8], lbv[8];
#pragma unroll
        for (int ct = 0; ct < 8; ++ct) {
            int col = wc * 128 + ct * 16 + l15;
            mbv[ct] = MB[col]; lsv[ct] = LS[col]; lbv[ct] = LB[col];
        }
#pragma unroll
        for (int reg = 0; reg < 4; ++reg) {
            float p = 0.f, q = 0.f;
#pragma unroll
            for (int ct = 0; ct < 8; ++ct) {
                float y = acc[ct][reg] + mbv[ct];
                acc[ct][reg] = y;
                p += y; q += y * y;
            }
#pragma unroll
            for (int d = 1; d < 16; d <<= 1) { p += __shfl_xor(p, d); q += __shfl_xor(q, d); }
            if (l15 == 0) {
                int row = wr * 16 + lg * 4 + reg;
                red[row * 4 + wc] = make_float2(p, q);
            }
        }
        __syncthreads();
#pragma unroll
        for (int reg = 0; reg < 4; ++reg) {
            int row = wr * 16 + lg * 4 + reg;
            float2 r0 = red[row * 4 + 0], r1 = red[row * 4 + 1];
            float2 r2 = red[row * 4 + 2], r3 = red[row * 4 + 3];
            float S = r0.x + r1.x + r2.x + r3.x;
            float S2 = r0.y + r1.y + r2.y + r3.y;
            float mu = S * (1.f / 512.f);
            float var = S2 * (1.f / 512.f) - mu * mu;
            float rs = rsqrtf(var + 1e-5f);
            int rswz = (row & 7) << 4;
#pragma unroll
            for (int ct = 0; ct < 8; ++ct) {
                float h = (acc[ct][reg] - mu) * rs * lsv[ct] + lbv[ct];
                h = fmaxf(h, 0.f);
                int col = wc * 128 + ct * 16 + l15;
                int addr = (row * 1024 + col * 2) ^ rswz;
                *(unsigned short*)(hx + addr) = f2bf(h);
            }
        }
        __syncthreads();
    }

    f32x4 a2[2];
#pragma unroll
    for (int ct = 0; ct < 2; ++ct) a2[ct] = (f32x4)(0.f);
    for (int kt = 0; kt < 16; ++kt) {
        U4B b[2];
#pragma unroll
        for (int ct = 0; ct < 2; ++ct)
            b[ct].u = *(const uint4*)(bb + (((size_t)wc * 2 + ct) * 64 + lane) * 16);
        U4B a;
        {
            int row = wr * 16 + l15;
            int addr = (row * 1024 + kt * 64 + lg * 16) ^ ((row & 7) << 4);
            a.u = *(const uint4*)(hx + addr);
        }
        __syncthreads();
        if (kt < 15) stage8(1024 + (kt + 1) * 8);
        __builtin_amdgcn_s_setprio(1);
#pragma unroll
        for (int ct = 0; ct < 2; ++ct)
            a2[ct] = __builtin_amdgcn_mfma_f32_16x16x32_bf16(a.v, b[ct].v, a2[ct], 0, 0, 0);
        __builtin_amdgcn_s_setprio(0);
        __syncthreads();
    }
    float mb2v[2];
#pragma unroll
    for (int ct = 0; ct < 2; ++ct) mb2v[ct] = mb2[wc * 32 + ct * 16 + l15];
#pragma unroll
    for (int reg = 0; reg < 4; ++reg) {
        int node = base + wr * 16 + lg * 4 + reg;
        if (node < n) {
#pragma unroll
            for (int ct = 0; ct < 2; ++ct)
                __builtin_nontemporal_store(a2[ct][reg] + mb2v[ct],
                    &out[(size_t)node * 128 + wc * 32 + ct * 16 + l15]);
        }
    }
}

extern "C" void kernel_launch(void* const* d_in, const int* in_sizes, int n_in,
                              void* d_out, int out_size, void* d_ws, size_t ws_size,
                              hipStream_t stream) {
    const int*   edges     = (const int*)d_in[0];
    const float* nf        = (const float*)d_in[1];
    const float* ea        = (const float*)d_in[2];
    const float* u         = (const float*)d_in[3];
    const int*   num_nodes = (const int*)d_in[4];
    const float* w1  = (const float*)d_in[5];
    const float* b1  = (const float*)d_in[6];
    const float* w2  = (const float*)d_in[7];
    const float* w3  = (const float*)d_in[8];
    const float* b3  = (const float*)d_in[9];
    const float* mw0 = (const float*)d_in[10];
    const float* mb0 = (const float*)d_in[11];
    const float* ls0 = (const float*)d_in[12];
    const float* lb0 = (const float*)d_in[13];
    const float* mw1 = (const float*)d_in[14];
    const float* mb1 = (const float*)d_in[15];
    const float* ls1 = (const float*)d_in[16];
    const float* lb1 = (const float*)d_in[17];
    const float* mw2 = (const float*)d_in[18];
    const float* mb2 = (const float*)d_in[19];

    int E = in_sizes[0] / 2;
    int n = in_sizes[1] / LATENT;
    int G = in_sizes[4];
    float* out = (float*)d_out;

    char* wsb = (char*)d_ws;
    size_t off = 0;
    auto alloc = [&](size_t bytes) { void* p = (void*)(wsb + off); off += (bytes + 15) & ~(size_t)15; return p; };
    uint4*          pw     = (uint4*)alloc((size_t)1312 * 64 * 16);
    unsigned short* PQK    = (unsigned short*)alloc((size_t)n * 256 * 2);
    unsigned short* PVh    = (unsigned short*)alloc((size_t)n * 128 * 2);
    unsigned short* Vs     = (unsigned short*)alloc((size_t)E * 128 * 2);
    unsigned short* Vr     = (unsigned short*)alloc((size_t)E * 128 * 2);
    float*          ess2   = (float*)alloc((size_t)E * 2 * 4);
    float*          ers2   = (float*)alloc((size_t)E * 2 * 4);
    unsigned short* out_sh = (unsigned short*)alloc((size_t)n * 128 * 2);
    unsigned short* out_rh = (unsigned short*)alloc((size_t)n * 128 * 2);
    int*            gid    = (int*)alloc((size_t)n * 4);
    int*            deg_s  = (int*)alloc((size_t)n * 4);   // zero region (deg_s, deg_r contiguous)
    int*            deg_r  = (int*)alloc((size_t)n * 4);
    int*            cur_s  = (int*)alloc((size_t)n * 4);
    int*            cur_r  = (int*)alloc((size_t)n * 4);
    int*            rps    = (int*)alloc((size_t)(n + 1) * 4);
    int*            rpr    = (int*)alloc((size_t)(n + 1) * 4);
    int*            sm_s   = (int*)alloc((size_t)E * 4);
    int*            sm_r   = (int*)alloc((size_t)E * 4);
    int*            goff   = (int*)alloc((size_t)(G + 1) * 4);
    int*            gcur   = (int*)alloc((size_t)(G + 1) * 4);

    hipMemsetAsync(deg_s, 0, (size_t)2 * n * 4 + 16, stream);

    hipFuncSetAttribute((const void*)k_mlp12, hipFuncAttributeMaxDynamicSharedMemorySize, 66560);

    k_scan<<<1, 1024, 0, stream>>>(num_nodes, G, goff, gcur);
    k_gidfill<<<(n + 255) / 256, 256, 0, stream>>>(goff, G, n, gid);
    k_pack2<<<(1312 * 64 + 255) / 256, 256, 0, stream>>>(mw0, mw1, mw2, w1, w3, pw);
    k_count<<<(E + 255) / 256, 256, 0, stream>>>(edges, E, deg_s, deg_r);
    k_scan<<<1, 1024, 0, stream>>>(deg_s, n, rps, cur_s);
    k_scan<<<1, 1024, 0, stream>>>(deg_r, n, rpr, cur_r);
    k_fill<<<(E + 255) / 256, 256, 0, stream>>>(edges, E, cur_s, cur_r, sm_s, sm_r);
    k_nodepre2<<<(n + 127) / 128, 512, 0, stream>>>(nf, n, pw, PQK, PVh);
    k_eproj1<<<(E + 63) / 64, 256, 0, stream>>>(edges, ea, E, pw, PQK, PVh, b1, w2, b3,
                                                sm_s, sm_r, Vs, Vr, ess2, ers2);
    k_aggr<<<(2 * n + 3) / 4, 256, 0, stream>>>(n, rps, rpr, ess2, ers2, Vs, Vr, out_sh, out_rh);
    k_mlp12<<<(n + 31) / 32, 512, 66560, stream>>>(nf, out_sh, out_rh, u, gid, n, pw,
                                                   mb0, ls0, lb0, mb1, ls1, lb1, mb2, out);
}

// Round 20
// 744.902 us; speedup vs baseline: 1.0458x; 1.0458x over previous
//
#include <hip/hip_runtime.h>
#include <math.h>

#define LATENT 128

typedef __attribute__((ext_vector_type(8))) short bf16x8;
typedef __attribute__((ext_vector_type(4))) float f32x4;
typedef __attribute__((ext_vector_type(2))) float f32x2;
typedef __attribute__((ext_vector_type(2))) unsigned u32x2;
typedef __attribute__((ext_vector_type(4))) unsigned u32x4;

union U4B { uint4 u; bf16x8 v; };

template <typename T>
__device__ __forceinline__ T ntl(const T* p) { return __builtin_nontemporal_load(p); }

__device__ __forceinline__ unsigned short f2bf(float f) {
    unsigned int x = __float_as_uint(f);
    unsigned int r = (x + 0x7fffu + ((x >> 16) & 1u)) >> 16;   // RNE
    return (unsigned short)r;
}
__device__ __forceinline__ float bf2f(unsigned short h) {
    return __uint_as_float(((unsigned int)h) << 16);
}
__device__ __forceinline__ unsigned pk2(float a, float b) {
    return (unsigned)f2bf(a) | ((unsigned)f2bf(b) << 16);
}
__device__ __forceinline__ float lo16(unsigned u) { return __uint_as_float(u << 16); }
__device__ __forceinline__ float hi16(unsigned u) { return __uint_as_float(u & 0xffff0000u); }

// direct global->LDS DMA, 16B per lane (wave-uniform LDS base + lane*16)
__device__ __forceinline__ void gld16(const void* g, void* l) {
    __builtin_amdgcn_global_load_lds(
        (const __attribute__((address_space(1))) unsigned int*)g,
        (__attribute__((address_space(3))) unsigned int*)l, 16, 0, 0);
}

// ---------------- graph-id: binary search over offsets ----------------
__global__ void k_gidfill(const int* __restrict__ goff, int G, int n, int* __restrict__ gid) {
    int i = blockIdx.x * 256 + threadIdx.x;
    if (i >= n) return;
    int lo = 0, hi = G - 1;
    while (lo < hi) {
        int mid = (lo + hi + 1) >> 1;
        if (goff[mid] <= i) lo = mid; else hi = mid - 1;
    }
    gid[i] = lo;
}

// ---------------- weight pack: fp32 row-major [K][N] -> bf16 MFMA-B frags ----
#define FN  1152
#define FE3 1248
#define FEV 1280
__global__ __launch_bounds__(256) void k_pack2(const float* __restrict__ mw0,
                                               const float* __restrict__ mw1,
                                               const float* __restrict__ mw2,
                                               const float* __restrict__ w1,
                                               const float* __restrict__ w3,
                                               uint4* __restrict__ pw) {
    int tid = blockIdx.x * 256 + threadIdx.x;
    if (tid >= 1312 * 64) return;
    int fid = tid >> 6, lane = tid & 63;
    const float* src; int kt, nt, N;
    if (fid < 512)       { src = mw0;            kt = fid >> 5;           nt = fid & 31;           N = 512; }
    else if (fid < 1024) { src = mw1;            kt = (fid - 512) >> 5;   nt = (fid - 512) & 31;   N = 512; }
    else if (fid < 1152) { src = mw2;            kt = (fid - 1024) >> 3;  nt = (fid - 1024) & 7;   N = 128; }
    else if (fid < 1184) { src = w1;             kt = (fid - 1152) >> 3;  nt = (fid - 1152) & 7;   N = 128; }
    else if (fid < 1216) { src = w1 + 128 * 128; kt = (fid - 1184) >> 3;  nt = (fid - 1184) & 7;   N = 128; }
    else if (fid < 1248) { src = w3;             kt = (fid - 1216) >> 3;  nt = (fid - 1216) & 7;   N = 128; }
    else if (fid < 1280) { src = w1 + 256 * 128; kt = (fid - 1248) >> 3;  nt = (fid - 1248) & 7;   N = 128; }
    else                 { src = w3 + 128 * 128; kt = (fid - 1280) >> 3;  nt = (fid - 1280) & 7;   N = 128; }
    int col = nt * 16 + (lane & 15);
    int k0 = kt * 32 + (lane >> 4) * 8;
    unsigned int w[4];
#pragma unroll
    for (int p = 0; p < 4; ++p) {
        unsigned int lo = f2bf(src[(size_t)(k0 + 2 * p) * N + col]);
        unsigned int hi = f2bf(src[(size_t)(k0 + 2 * p + 1) * N + col]);
        w[p] = lo | (hi << 16);
    }
    pw[(size_t)fid * 64 + lane] = make_uint4(w[0], w[1], w[2], w[3]);
}

// ---------------- CSR build ----------------
__global__ void k_count(const int* __restrict__ edges, int E,
                        int* __restrict__ deg_s, int* __restrict__ deg_r) {
    int e = blockIdx.x * 256 + threadIdx.x;
    if (e < E) { atomicAdd(&deg_s[edges[e]], 1); atomicAdd(&deg_r[edges[E + e]], 1); }
}

// parallel two-level shuffle scan (1024 threads)
__global__ __launch_bounds__(1024) void k_scan(const int* __restrict__ deg, int n,
                                               int* __restrict__ rowptr, int* __restrict__ cursor) {
    __shared__ int wsum[16];
    int t = threadIdx.x;
    int chunk = (n + 1023) / 1024;
    int s = t * chunk; if (s > n) s = n;
    int epos = s + chunk; if (epos > n) epos = n;
    int sum = 0;
    for (int i = s; i < epos; ++i) sum += deg[i];
    int lane = t & 63, wid = t >> 6;
    int v = sum;
#pragma unroll
    for (int d = 1; d < 64; d <<= 1) { int o = __shfl_up(v, d); if (lane >= d) v += o; }
    if (lane == 63) wsum[wid] = v;
    __syncthreads();
    if (t < 16) {
        int wv = wsum[t];
#pragma unroll
        for (int d = 1; d < 16; d <<= 1) { int o = __shfl_up(wv, d, 16); if (t >= d) wv += o; }
        wsum[t] = wv;
    }
    __syncthreads();
    int woff = wid ? wsum[wid - 1] : 0;
    int run = v + woff - sum;   // exclusive prefix of this thread's chunk
    for (int i = s; i < epos; ++i) { rowptr[i] = run; if (cursor) cursor[i] = run; run += deg[i]; }
    if (t == 1023) rowptr[n] = run;
}

// fill: inverse slot maps only
__global__ void k_fill(const int* __restrict__ edges, int E,
                       int* __restrict__ cur_s, int* __restrict__ cur_r,
                       int* __restrict__ sm_s, int* __restrict__ sm_r) {
    int e = blockIdx.x * 256 + threadIdx.x;
    if (e < E) {
        int r = edges[e], c = edges[E + e];
        sm_s[e] = atomicAdd(&cur_s[r], 1);
        sm_r[e] = atomicAdd(&cur_r[c], 1);
    }
}

// ---------------- node projections (MFMA): PQK=[nf@W1q | nf@W1k], PV=nf@W3k (bf16)
__global__ __launch_bounds__(512) void k_nodepre2(const float* __restrict__ nf, int n,
                                                  const uint4* __restrict__ pw,
                                                  unsigned short* __restrict__ PQK,
                                                  unsigned short* __restrict__ PVh) {
    __shared__ uint4 xs[32 * 64];   // 32KB, A-frags: [kt4][rtile8][lane64]
    int t = threadIdx.x, lane = t & 63, w = t >> 6;
    int wr = w >> 2, wc = w & 3, l15 = lane & 15, lg = lane >> 4;
    int base = blockIdx.x * 128;
#pragma unroll
    for (int it = 0; it < 4; ++it) {
        int chunk = t + it * 512;
        int row = chunk >> 4, k8 = chunk & 15, k = k8 * 8;
        int node = base + row;
        f32x4 v0 = (f32x4)(0.f), v1 = (f32x4)(0.f);
        if (node < n) {
            const f32x4* s4 = (const f32x4*)(nf + (size_t)node * 128 + k);
            v0 = ntl(s4); v1 = ntl(s4 + 1);
        }
        uint4 pkv;
        pkv.x = pk2(v0.x, v0.y); pkv.y = pk2(v0.z, v0.w);
        pkv.z = pk2(v1.x, v1.y); pkv.w = pk2(v1.z, v1.w);
        int kt = k >> 5, g = (k >> 3) & 3;
        xs[(kt * 8 + (row >> 4)) * 64 + g * 16 + (row & 15)] = pkv;
    }
    __syncthreads();
    f32x4 acc[4][6];
#pragma unroll
    for (int rt = 0; rt < 4; ++rt)
#pragma unroll
        for (int ct = 0; ct < 6; ++ct) acc[rt][ct] = (f32x4)(0.f);
    for (int kt = 0; kt < 4; ++kt) {
        U4B a[4];
#pragma unroll
        for (int rt = 0; rt < 4; ++rt) a[rt].u = xs[(kt * 8 + wr * 4 + rt) * 64 + lane];
        U4B b[6];
#pragma unroll
        for (int ct = 0; ct < 6; ++ct) {
            int nt = wc * 6 + ct;
            int mat = nt >> 3, ntm = nt & 7;
            b[ct].u = pw[(size_t)(FN + mat * 32 + kt * 8 + ntm) * 64 + lane];
        }
#pragma unroll
        for (int rt = 0; rt < 4; ++rt)
#pragma unroll
            for (int ct = 0; ct < 6; ++ct)
                acc[rt][ct] = __builtin_amdgcn_mfma_f32_16x16x32_bf16(a[rt].v, b[ct].v, acc[rt][ct], 0, 0, 0);
    }
#pragma unroll
    for (int rt = 0; rt < 4; ++rt)
#pragma unroll
        for (int ct = 0; ct < 6; ++ct) {
            int nt = wc * 6 + ct;
#pragma unroll
            for (int reg = 0; reg < 4; ++reg) {
                int node = base + (wr * 4 + rt) * 16 + lg * 4 + reg;
                if (node < n) {
                    unsigned short hv = f2bf(acc[rt][ct][reg]);
                    if (nt < 16) PQK[(size_t)node * 256 + nt * 16 + l15] = hv;
                    else         PVh[(size_t)node * 128 + (nt - 16) * 16 + l15] = hv;
                }
            }
        }
}

// ---------------- edge projection (MFMA, 2 rt-passes @32 AGPR) + logits/exp;
// V = (EV+b3)+PV[other] to both slot orders. LDS 48KB: xs16 | ldsE16 | ldsV16.
// edata/evdata rows XOR-swizzled: byte ^= (e_loc&7)<<4
__global__ __launch_bounds__(256) void k_eproj1(const int* __restrict__ edges,
                                                const float* __restrict__ ea, int E,
                                                const uint4* __restrict__ pw,
                                                const unsigned short* __restrict__ PQK,
                                                const unsigned short* __restrict__ PVh,
                                                const float* __restrict__ b1,
                                                const float* __restrict__ w2,
                                                const float* __restrict__ b3,
                                                const int* __restrict__ sm_s,
                                                const int* __restrict__ sm_r,
                                                unsigned short* __restrict__ Vs,
                                                unsigned short* __restrict__ Vr,
                                                float* __restrict__ ess2, float* __restrict__ ers2) {
    __shared__ char lds[49152];
    uint4* xs = (uint4*)lds;          // 16KB A-frags (live through both passes)
    char* ldsE = lds + 16384;         // E3 + b1 rows
    char* ldsV = lds + 32768;         // EV + b3 rows
    int t = threadIdx.x, lane = t & 63, w = t >> 6;
    int wc = w, l15 = lane & 15, lg = lane >> 4;
    int base = blockIdx.x * 64;
#pragma unroll
    for (int it = 0; it < 4; ++it) {
        int chunk = t + it * 256;
        int row = chunk >> 4, k8 = chunk & 15, k = k8 * 8;
        int e = base + row;
        f32x4 v0 = (f32x4)(0.f), v1 = (f32x4)(0.f);
        if (e < E) {
            const f32x4* s4 = (const f32x4*)(ea + (size_t)e * 128 + k);
            v0 = ntl(s4); v1 = ntl(s4 + 1);
        }
        uint4 pkv;
        pkv.x = pk2(v0.x, v0.y); pkv.y = pk2(v0.z, v0.w);
        pkv.z = pk2(v1.x, v1.y); pkv.w = pk2(v1.z, v1.w);
        int kt = k >> 5, g = (k >> 3) & 3;
        xs[(kt * 4 + (row >> 4)) * 64 + g * 16 + (row & 15)] = pkv;
    }
    __syncthreads();
    // two passes over row-halves: acc[2][4] = 32 AGPR instead of 64
#pragma unroll
    for (int pass = 0; pass < 2; ++pass) {
        f32x4 acc[2][4];   // [rt2][ct]: ct 0,1 = E3 cols, ct 2,3 = EV cols
#pragma unroll
        for (int rt2 = 0; rt2 < 2; ++rt2)
#pragma unroll
            for (int ct = 0; ct < 4; ++ct) acc[rt2][ct] = (f32x4)(0.f);
        for (int kt = 0; kt < 4; ++kt) {
            U4B a[2];
#pragma unroll
            for (int rt2 = 0; rt2 < 2; ++rt2)
                a[rt2].u = xs[(kt * 4 + pass * 2 + rt2) * 64 + lane];
            U4B b[4];
            b[0].u = pw[(size_t)(FE3 + kt * 8 + wc * 2 + 0) * 64 + lane];
            b[1].u = pw[(size_t)(FE3 + kt * 8 + wc * 2 + 1) * 64 + lane];
            b[2].u = pw[(size_t)(FEV + kt * 8 + wc * 2 + 0) * 64 + lane];
            b[3].u = pw[(size_t)(FEV + kt * 8 + wc * 2 + 1) * 64 + lane];
#pragma unroll
            for (int rt2 = 0; rt2 < 2; ++rt2)
#pragma unroll
                for (int ct = 0; ct < 4; ++ct)
                    acc[rt2][ct] = __builtin_amdgcn_mfma_f32_16x16x32_bf16(a[rt2].v, b[ct].v, acc[rt2][ct], 0, 0, 0);
        }
        // E3+b1 -> ldsE, EV+b3 -> ldsV; swizzled rows (disjoint rows per pass)
#pragma unroll
        for (int rt2 = 0; rt2 < 2; ++rt2)
#pragma unroll
            for (int cc = 0; cc < 2; ++cc) {
                int col = (wc * 2 + cc) * 16 + l15;
                float b1c = b1[col], b3c = b3[col];
#pragma unroll
                for (int reg = 0; reg < 4; ++reg) {
                    int e_loc = (pass * 2 + rt2) * 16 + lg * 4 + reg;
                    int off = (e_loc * 256 + col * 2) ^ ((e_loc & 7) << 4);
                    *(unsigned short*)(ldsE + off) = f2bf(acc[rt2][cc][reg] + b1c);
                    *(unsigned short*)(ldsV + off) = f2bf(acc[rt2][2 + cc][reg] + b3c);
                }
            }
    }
    __syncthreads();
    // scatter V = (EV+b3) + PV[other] to both slot orders (256B rows, 16 lanes x 16B)
    {
        int e4 = lane >> 4, piece = lane & 15;
#pragma unroll
        for (int i = 0; i < 4; ++i) {
            int e_loc = w * 16 + i * 4 + e4;
            int e = base + e_loc;
            if (e < E) {
                int r = edges[e], c = edges[E + e];
                int off = (e_loc * 256 + piece * 16) ^ ((e_loc & 7) << 4);
                u32x4 vev = *(const u32x4*)(ldsV + off);
                u32x4 pvc = *(const u32x4*)(PVh + (size_t)c * 128 + piece * 8);
                u32x4 pvr = *(const u32x4*)(PVh + (size_t)r * 128 + piece * 8);
                u32x4 vs, vr;
#pragma unroll
                for (int q = 0; q < 4; ++q) {
                    float e0 = lo16(vev[q]);
                    float e1 = hi16(vev[q]);
                    vs[q] = pk2(e0 + lo16(pvc[q]), e1 + hi16(pvc[q]));
                    vr[q] = pk2(e0 + lo16(pvr[q]), e1 + hi16(pvr[q]));
                }
                __builtin_nontemporal_store(vs, (u32x4*)(Vs + (size_t)sm_s[e] * 128 + piece * 8));
                __builtin_nontemporal_store(vr, (u32x4*)(Vr + (size_t)sm_r[e] * 128 + piece * 8));
            }
        }
    }
    int esub = lane >> 3, dg = lane & 7;
    float w2r[16];
    {
        const float4* w4 = (const float4*)(w2 + (dg >> 2) * 64 + (dg & 3) * 16);
#pragma unroll
        for (int q = 0; q < 4; ++q) {
            float4 wv = w4[q];
            w2r[q * 4 + 0] = wv.x; w2r[q * 4 + 1] = wv.y; w2r[q * 4 + 2] = wv.z; w2r[q * 4 + 3] = wv.w;
        }
    }
#pragma unroll
    for (int it = 0; it < 2; ++it) {
        int e_loc = w * 16 + it * 8 + esub;
        int e = base + e_loc;
        if (e >= E) break;
        int r = edges[e], c = edges[E + e];
        const uint4* Aqr = (const uint4*)(PQK + ((size_t)r << 8) + dg * 16);
        const uint4* Akc = (const uint4*)(PQK + ((size_t)c << 8) + 128 + dg * 16);
        const uint4* Aqc = (const uint4*)(PQK + ((size_t)c << 8) + dg * 16);
        const uint4* Akr = (const uint4*)(PQK + ((size_t)r << 8) + 128 + dg * 16);
        float ps = 0.f, pr = 0.f;
#pragma unroll
        for (int half = 0; half < 2; ++half) {
            int off3 = (e_loc * 256 + dg * 32 + half * 16) ^ ((e_loc & 7) << 4);
            uint4 ue3 = *(const uint4*)(ldsE + off3);
            uint4 uqr = Aqr[half], ukc = Akc[half], uqc = Aqc[half], ukr = Akr[half];
            unsigned wqr[4] = {uqr.x, uqr.y, uqr.z, uqr.w};
            unsigned wkc[4] = {ukc.x, ukc.y, ukc.z, ukc.w};
            unsigned wqc[4] = {uqc.x, uqc.y, uqc.z, uqc.w};
            unsigned wkr[4] = {ukr.x, ukr.y, ukr.z, ukr.w};
            unsigned we3[4] = {ue3.x, ue3.y, ue3.z, ue3.w};
#pragma unroll
            for (int q = 0; q < 4; ++q) {
#pragma unroll
                for (int hl = 0; hl < 2; ++hl) {
                    int i = half * 8 + q * 2 + hl;
                    float fqr = hl ? hi16(wqr[q]) : lo16(wqr[q]);
                    float fkc = hl ? hi16(wkc[q]) : lo16(wkc[q]);
                    float fqc = hl ? hi16(wqc[q]) : lo16(wqc[q]);
                    float fkr = hl ? hi16(wkr[q]) : lo16(wkr[q]);
                    float com = hl ? hi16(we3[q]) : lo16(we3[q]);   // e3 + b1 prefolded
                    float hs = fqr + fkc + com; hs = hs > 0.f ? hs : 0.2f * hs;
                    float hr = fqc + fkr + com; hr = hr > 0.f ? hr : 0.2f * hr;
                    ps += hs * w2r[i]; pr += hr * w2r[i];
                }
            }
        }
        ps += __shfl_xor(ps, 1); ps += __shfl_xor(ps, 2);
        pr += __shfl_xor(pr, 1); pr += __shfl_xor(pr, 2);
        float Es = expf(ps), Er = expf(pr);
        if (dg == 0) {
            __builtin_nontemporal_store(Es, &ess2[(size_t)sm_s[e] * 2]);
            __builtin_nontemporal_store(Er, &ers2[(size_t)sm_r[e] * 2]);
        } else if (dg == 4) {
            __builtin_nontemporal_store(Es, &ess2[(size_t)sm_s[e] * 2 + 1]);
            __builtin_nontemporal_store(Er, &ers2[(size_t)sm_r[e] * 2 + 1]);
        }
    }
}

// ---------------- per-node aggregate: fully slot-sequential streaming ----
__global__ __launch_bounds__(256) void k_aggr(int n,
                                              const int* __restrict__ rps, const int* __restrict__ rpr,
                                              const float* __restrict__ ess2, const float* __restrict__ ers2,
                                              const unsigned short* __restrict__ Vs,
                                              const unsigned short* __restrict__ Vr,
                                              unsigned short* __restrict__ out_sh,
                                              unsigned short* __restrict__ out_rh) {
    int w = threadIdx.x >> 6, lane = threadIdx.x & 63;
    int unit = blockIdx.x * 4 + w;
    if (unit >= 2 * n) return;
    bool sent = unit < n;
    int node = sent ? unit : unit - n;
    const int*      rp = sent ? rps : rpr;
    const float*    ex = sent ? ess2 : ers2;
    const unsigned* V  = (const unsigned*)(sent ? Vs : Vr);
    int s0 = rp[node], s1 = rp[node + 1];
    float z0 = 0.f, z1 = 0.f, acca = 0.f, accb = 0.f;
    int j = s0;
    for (; j + 4 <= s1; j += 4) {
        f32x2 ez[4]; unsigned v[4];
#pragma unroll
        for (int q = 0; q < 4; ++q) ez[q] = ntl((const f32x2*)(ex + 2 * (j + q)));
#pragma unroll
        for (int q = 0; q < 4; ++q) v[q] = ntl(V + (size_t)(j + q) * 64 + lane);
#pragma unroll
        for (int q = 0; q < 4; ++q) {
            z0 += ez[q].x; z1 += ez[q].y;
            float aw = (lane < 32) ? ez[q].x : ez[q].y;
            acca += aw * lo16(v[q]); accb += aw * hi16(v[q]);
        }
    }
    for (; j < s1; ++j) {
        f32x2 ez = ntl((const f32x2*)(ex + 2 * j));
        unsigned v = ntl(V + (size_t)j * 64 + lane);
        z0 += ez.x; z1 += ez.y;
        float aw = (lane < 32) ? ez.x : ez.y;
        acca += aw * lo16(v); accb += aw * hi16(v);
    }
    float zz = (lane < 32) ? z0 : z1;
    float rz = 1.f / (zz + 1e-16f);
    unsigned o = pk2(acca * rz, accb * rz);
    unsigned* outp = (unsigned*)(sent ? out_sh : out_rh);
    outp[(size_t)node * 64 + lane] = o;
}

// ---------------- fused MFMA MLP v12: 32-row tile, 8 waves, 2 blocks/CU, 32-AGPR acc ----
__global__ __launch_bounds__(512, 4) void k_mlp12(
    const float* __restrict__ nf, const unsigned short* __restrict__ out_sh,
    const unsigned short* __restrict__ out_rh,
    const float* __restrict__ u, const int* __restrict__ gid, int n,
    const uint4* __restrict__ pw,
    const float* __restrict__ mb0, const float* __restrict__ ls0, const float* __restrict__ lb0,
    const float* __restrict__ mb1, const float* __restrict__ ls1, const float* __restrict__ lb1,
    const float* __restrict__ mb2, float* __restrict__ out) {
    extern __shared__ char smem[];
    char* hx = smem;                           // 32 KB
    char* bb = smem + 32768;                   // 32 KB
    float2* red = (float2*)(smem + 65536);     // [32][4]

    int t = threadIdx.x, lane = t & 63, w = t >> 6;   // 8 waves: 2 row x 4 col
    int wr = w >> 2, wc = w & 3, l15 = lane & 15, lg = lane >> 4;
    int base = blockIdx.x * 32;

    auto stage32 = [&](int fragbase) {
        const uint4* src = pw + (size_t)fragbase * 64;
#pragma unroll
        for (int q = 0; q < 4; ++q)
            gld16(src + q * 512 + t, bb + ((size_t)q * 512 + t) * 16);
    };
    auto stage8 = [&](int fragbase) {
        const uint4* src = pw + (size_t)fragbase * 64;
        gld16(src + t, bb + (size_t)t * 16);
    };

    stage32(0);
#pragma unroll
    for (int it = 0; it < 8; ++it) {
        int chunk = t + it * 512;
        int row = chunk >> 7, kq = chunk & 127;
        int k = kq * 4;
        int node = base + row;
        u32x2 p = (u32x2)(0u);
        if (node < n) {
            int kk = k & 127;
            if (k < 128) {
                f32x4 v = ntl((const f32x4*)(nf + (size_t)node * 128 + kk));
                p.x = pk2(v.x, v.y); p.y = pk2(v.z, v.w);
            } else if (k < 384) {
                const unsigned short* s = (k < 256 ? out_sh : out_rh) + (size_t)node * 128 + kk;
                p = ntl((const u32x2*)s);
            } else {
                f32x4 v = *(const f32x4*)(u + (size_t)gid[node] * 128 + kk);
                p.x = pk2(v.x, v.y); p.y = pk2(v.z, v.w);
            }
        }
        int addr = (row * 1024 + k * 2) ^ ((row & 7) << 4);
        *(u32x2*)(hx + addr) = p;
    }
    __syncthreads();

    f32x4 acc[8];
#pragma unroll
    for (int layer = 0; layer < 2; ++layer) {
        const float* MB = layer ? mb1 : mb0;
        const float* LS = layer ? ls1 : ls0;
        const float* LB = layer ? lb1 : lb0;
        const int fbase = layer ? 512 : 0;
#pragma unroll
        for (int ct = 0; ct < 8; ++ct) acc[ct] = (f32x4)(0.f);

        for (int kt = 0; kt < 16; ++kt) {
            U4B b[8];
#pragma unroll
            for (int ct = 0; ct < 8; ++ct)
                b[ct].u = *(const uint4*)(bb + (((size_t)wc * 8 + ct) * 64 + lane) * 16);
            U4B a;
            {
                int row = wr * 16 + l15;
                int addr = (row * 1024 + kt * 64 + lg * 16) ^ ((row & 7) << 4);
                a.u = *(const uint4*)(hx + addr);
            }
            __syncthreads();
            if (kt < 15)            stage32(fbase + (kt + 1) * 32);
            else if (layer == 0)    stage32(512);
            else                    stage8(1024);
            __builtin_amdgcn_s_setprio(1);
#pragma unroll
            for (int ct = 0; ct < 8; ++ct)
                acc[ct] = __builtin_amdgcn_mfma_f32_16x16x32_bf16(a.v, b[ct].v, acc[ct], 0, 0, 0);
            __builtin_amdgcn_s_setprio(0);
            __syncthreads();
        }

        float mbv[8], lsv[8], lbv[8];
#pragma unroll
        for (int ct = 0; ct < 8; ++ct) {
            int col = wc * 128 + ct * 16 + l15;
            mbv[ct] = MB[col]; lsv[ct] = LS[col]; lbv[ct] = LB[col];
        }
#pragma unroll
        for (int reg = 0; reg < 4; ++reg) {
            float p = 0.f, q = 0.f;
#pragma unroll
            for (int ct = 0; ct < 8; ++ct) {
                float y = acc[ct][reg] + mbv[ct];
                acc[ct][reg] = y;
                p += y; q += y * y;
            }
#pragma unroll
            for (int d = 1; d < 16; d <<= 1) { p += __shfl_xor(p, d); q += __shfl_xor(q, d); }
            if (l15 == 0) {
                int row = wr * 16 + lg * 4 + reg;
                red[row * 4 + wc] = make_float2(p, q);
            }
        }
        __syncthreads();
#pragma unroll
        for (int reg = 0; reg < 4; ++reg) {
            int row = wr * 16 + lg * 4 + reg;
            float2 r0 = red[row * 4 + 0], r1 = red[row * 4 + 1];
            float2 r2 = red[row * 4 + 2], r3 = red[row * 4 + 3];
            float S = r0.x + r1.x + r2.x + r3.x;
            float S2 = r0.y + r1.y + r2.y + r3.y;
            float mu = S * (1.f / 512.f);
            float var = S2 * (1.f / 512.f) - mu * mu;
            float rs = rsqrtf(var + 1e-5f);
            int rswz = (row & 7) << 4;
#pragma unroll
            for (int ct = 0; ct < 8; ++ct) {
                float h = (acc[ct][reg] - mu) * rs * lsv[ct] + lbv[ct];
                h = fmaxf(h, 0.f);
                int col = wc * 128 + ct * 16 + l15;
                int addr = (row * 1024 + col * 2) ^ rswz;
                *(unsigned short*)(hx + addr) = f2bf(h);
            }
        }
        __syncthreads();
    }

    f32x4 a2[2];
#pragma unroll
    for (int ct = 0; ct < 2; ++ct) a2[ct] = (f32x4)(0.f);
    for (int kt = 0; kt < 16; ++kt) {
        U4B b[2];
#pragma unroll
        for (int ct = 0; ct < 2; ++ct)
            b[ct].u = *(const uint4*)(bb + (((size_t)wc * 2 + ct) * 64 + lane) * 16);
        U4B a;
        {
            int row = wr * 16 + l15;
            int addr = (row * 1024 + kt * 64 + lg * 16) ^ ((row & 7) << 4);
            a.u = *(const uint4*)(hx + addr);
        }
        __syncthreads();
        if (kt < 15) stage8(1024 + (kt + 1) * 8);
        __builtin_amdgcn_s_setprio(1);
#pragma unroll
        for (int ct = 0; ct < 2; ++ct)
            a2[ct] = __builtin_amdgcn_mfma_f32_16x16x32_bf16(a.v, b[ct].v, a2[ct], 0, 0, 0);
        __builtin_amdgcn_s_setprio(0);
        __syncthreads();
    }
    float mb2v[2];
#pragma unroll
    for (int ct = 0; ct < 2; ++ct) mb2v[ct] = mb2[wc * 32 + ct * 16 + l15];
#pragma unroll
    for (int reg = 0; reg < 4; ++reg) {
        int node = base + wr * 16 + lg * 4 + reg;
        if (node < n) {
#pragma unroll
            for (int ct = 0; ct < 2; ++ct)
                __builtin_nontemporal_store(a2[ct][reg] + mb2v[ct],
                    &out[(size_t)node * 128 + wc * 32 + ct * 16 + l15]);
        }
    }
}

extern "C" void kernel_launch(void* const* d_in, const int* in_sizes, int n_in,
                              void* d_out, int out_size, void* d_ws, size_t ws_size,
                              hipStream_t stream) {
    const int*   edges     = (const int*)d_in[0];
    const float* nf        = (const float*)d_in[1];
    const float* ea        = (const float*)d_in[2];
    const float* u         = (const float*)d_in[3];
    const int*   num_nodes = (const int*)d_in[4];
    const float* w1  = (const float*)d_in[5];
    const float* b1  = (const float*)d_in[6];
    const float* w2  = (const float*)d_in[7];
    const float* w3  = (const float*)d_in[8];
    const float* b3  = (const float*)d_in[9];
    const float* mw0 = (const float*)d_in[10];
    const float* mb0 = (const float*)d_in[11];
    const float* ls0 = (const float*)d_in[12];
    const float* lb0 = (const float*)d_in[13];
    const float* mw1 = (const float*)d_in[14];
    const float* mb1 = (const float*)d_in[15];
    const float* ls1 = (const float*)d_in[16];
    const float* lb1 = (const float*)d_in[17];
    const float* mw2 = (const float*)d_in[18];
    const float* mb2 = (const float*)d_in[19];

    int E = in_sizes[0] / 2;
    int n = in_sizes[1] / LATENT;
    int G = in_sizes[4];
    float* out = (float*)d_out;

    char* wsb = (char*)d_ws;
    size_t off = 0;
    auto alloc = [&](size_t bytes) { void* p = (void*)(wsb + off); off += (bytes + 15) & ~(size_t)15; return p; };
    uint4*          pw     = (uint4*)alloc((size_t)1312 * 64 * 16);
    unsigned short* PQK    = (unsigned short*)alloc((size_t)n * 256 * 2);
    unsigned short* PVh    = (unsigned short*)alloc((size_t)n * 128 * 2);
    unsigned short* Vs     = (unsigned short*)alloc((size_t)E * 128 * 2);
    unsigned short* Vr     = (unsigned short*)alloc((size_t)E * 128 * 2);
    float*          ess2   = (float*)alloc((size_t)E * 2 * 4);
    float*          ers2   = (float*)alloc((size_t)E * 2 * 4);
    unsigned short* out_sh = (unsigned short*)alloc((size_t)n * 128 * 2);
    unsigned short* out_rh = (unsigned short*)alloc((size_t)n * 128 * 2);
    int*            gid    = (int*)alloc((size_t)n * 4);
    int*            deg_s  = (int*)alloc((size_t)n * 4);   // zero region (deg_s, deg_r contiguous)
    int*            deg_r  = (int*)alloc((size_t)n * 4);
    int*            cur_s  = (int*)alloc((size_t)n * 4);
    int*            cur_r  = (int*)alloc((size_t)n * 4);
    int*            rps    = (int*)alloc((size_t)(n + 1) * 4);
    int*            rpr    = (int*)alloc((size_t)(n + 1) * 4);
    int*            sm_s   = (int*)alloc((size_t)E * 4);
    int*            sm_r   = (int*)alloc((size_t)E * 4);
    int*            goff   = (int*)alloc((size_t)(G + 1) * 4);
    int*            gcur   = (int*)alloc((size_t)(G + 1) * 4);

    hipMemsetAsync(deg_s, 0, (size_t)2 * n * 4 + 16, stream);

    hipFuncSetAttribute((const void*)k_mlp12, hipFuncAttributeMaxDynamicSharedMemorySize, 66560);

    k_scan<<<1, 1024, 0, stream>>>(num_nodes, G, goff, gcur);
    k_gidfill<<<(n + 255) / 256, 256, 0, stream>>>(goff, G, n, gid);
    k_pack2<<<(1312 * 64 + 255) / 256, 256, 0, stream>>>(mw0, mw1, mw2, w1, w3, pw);
    k_count<<<(E + 255) / 256, 256, 0, stream>>>(edges, E, deg_s, deg_r);
    k_scan<<<1, 1024, 0, stream>>>(deg_s, n, rps, cur_s);
    k_scan<<<1, 1024, 0, stream>>>(deg_r, n, rpr, cur_r);
    k_fill<<<(E + 255) / 256, 256, 0, stream>>>(edges, E, cur_s, cur_r, sm_s, sm_r);
    k_nodepre2<<<(n + 127) / 128, 512, 0, stream>>>(nf, n, pw, PQK, PVh);
    k_eproj1<<<(E + 63) / 64, 256, 0, stream>>>(edges, ea, E, pw, PQK, PVh, b1, w2, b3,
                                                sm_s, sm_r, Vs, Vr, ess2, ers2);
    k_aggr<<<(2 * n + 3) / 4, 256, 0, stream>>>(n, rps, rpr, ess2, ers2, Vs, Vr, out_sh, out_rh);
    k_mlp12<<<(n + 31) / 32, 512, 66560, stream>>>(nf, out_sh, out_rh, u, gid, n, pw,
                                                   mb0, ls0, lb0, mb1, ls1, lb1, mb2, out);
}

// Round 21
// 727.887 us; speedup vs baseline: 1.0702x; 1.0234x over previous
//
#include <hip/hip_runtime.h>
#include <math.h>

#define LATENT 128

typedef __attribute__((ext_vector_type(8))) short bf16x8;
typedef __attribute__((ext_vector_type(4))) float f32x4;
typedef __attribute__((ext_vector_type(2))) float f32x2;
typedef __attribute__((ext_vector_type(2))) unsigned u32x2;
typedef __attribute__((ext_vector_type(4))) unsigned u32x4;

union U4B { uint4 u; bf16x8 v; };

template <typename T>
__device__ __forceinline__ T ntl(const T* p) { return __builtin_nontemporal_load(p); }

__device__ __forceinline__ unsigned short f2bf(float f) {
    unsigned int x = __float_as_uint(f);
    unsigned int r = (x + 0x7fffu + ((x >> 16) & 1u)) >> 16;   // RNE
    return (unsigned short)r;
}
__device__ __forceinline__ float bf2f(unsigned short h) {
    return __uint_as_float(((unsigned int)h) << 16);
}
__device__ __forceinline__ unsigned pk2(float a, float b) {
    return (unsigned)f2bf(a) | ((unsigned)f2bf(b) << 16);
}
__device__ __forceinline__ float lo16(unsigned u) { return __uint_as_float(u << 16); }
__device__ __forceinline__ float hi16(unsigned u) { return __uint_as_float(u & 0xffff0000u); }

// ---------------- graph-id: binary search over offsets ----------------
__global__ void k_gidfill(const int* __restrict__ goff, int G, int n, int* __restrict__ gid) {
    int i = blockIdx.x * 256 + threadIdx.x;
    if (i >= n) return;
    int lo = 0, hi = G - 1;
    while (lo < hi) {
        int mid = (lo + hi + 1) >> 1;
        if (goff[mid] <= i) lo = mid; else hi = mid - 1;
    }
    gid[i] = lo;
}

// ---------------- weight pack: fp32 row-major [K][N] -> bf16 MFMA-B frags ----
#define FN  1152
#define FE3 1248
#define FEV 1280
__global__ __launch_bounds__(256) void k_pack2(const float* __restrict__ mw0,
                                               const float* __restrict__ mw1,
                                               const float* __restrict__ mw2,
                                               const float* __restrict__ w1,
                                               const float* __restrict__ w3,
                                               uint4* __restrict__ pw) {
    int tid = blockIdx.x * 256 + threadIdx.x;
    if (tid >= 1312 * 64) return;
    int fid = tid >> 6, lane = tid & 63;
    const float* src; int kt, nt, N;
    if (fid < 512)       { src = mw0;            kt = fid >> 5;           nt = fid & 31;           N = 512; }
    else if (fid < 1024) { src = mw1;            kt = (fid - 512) >> 5;   nt = (fid - 512) & 31;   N = 512; }
    else if (fid < 1152) { src = mw2;            kt = (fid - 1024) >> 3;  nt = (fid - 1024) & 7;   N = 128; }
    else if (fid < 1184) { src = w1;             kt = (fid - 1152) >> 3;  nt = (fid - 1152) & 7;   N = 128; }
    else if (fid < 1216) { src = w1 + 128 * 128; kt = (fid - 1184) >> 3;  nt = (fid - 1184) & 7;   N = 128; }
    else if (fid < 1248) { src = w3;             kt = (fid - 1216) >> 3;  nt = (fid - 1216) & 7;   N = 128; }
    else if (fid < 1280) { src = w1 + 256 * 128; kt = (fid - 1248) >> 3;  nt = (fid - 1248) & 7;   N = 128; }
    else                 { src = w3 + 128 * 128; kt = (fid - 1280) >> 3;  nt = (fid - 1280) & 7;   N = 128; }
    int col = nt * 16 + (lane & 15);
    int k0 = kt * 32 + (lane >> 4) * 8;
    unsigned int w[4];
#pragma unroll
    for (int p = 0; p < 4; ++p) {
        unsigned int lo = f2bf(src[(size_t)(k0 + 2 * p) * N + col]);
        unsigned int hi = f2bf(src[(size_t)(k0 + 2 * p + 1) * N + col]);
        w[p] = lo | (hi << 16);
    }
    pw[(size_t)fid * 64 + lane] = make_uint4(w[0], w[1], w[2], w[3]);
}

// ---------------- CSR build ----------------
__global__ void k_count(const int* __restrict__ edges, int E,
                        int* __restrict__ deg_s, int* __restrict__ deg_r) {
    int e = blockIdx.x * 256 + threadIdx.x;
    if (e < E) { atomicAdd(&deg_s[edges[e]], 1); atomicAdd(&deg_r[edges[E + e]], 1); }
}

// parallel two-level shuffle scan (1024 threads)
__global__ __launch_bounds__(1024) void k_scan(const int* __restrict__ deg, int n,
                                               int* __restrict__ rowptr, int* __restrict__ cursor) {
    __shared__ int wsum[16];
    int t = threadIdx.x;
    int chunk = (n + 1023) / 1024;
    int s = t * chunk; if (s > n) s = n;
    int epos = s + chunk; if (epos > n) epos = n;
    int sum = 0;
    for (int i = s; i < epos; ++i) sum += deg[i];
    int lane = t & 63, wid = t >> 6;
    int v = sum;
#pragma unroll
    for (int d = 1; d < 64; d <<= 1) { int o = __shfl_up(v, d); if (lane >= d) v += o; }
    if (lane == 63) wsum[wid] = v;
    __syncthreads();
    if (t < 16) {
        int wv = wsum[t];
#pragma unroll
        for (int d = 1; d < 16; d <<= 1) { int o = __shfl_up(wv, d, 16); if (t >= d) wv += o; }
        wsum[t] = wv;
    }
    __syncthreads();
    int woff = wid ? wsum[wid - 1] : 0;
    int run = v + woff - sum;   // exclusive prefix of this thread's chunk
    for (int i = s; i < epos; ++i) { rowptr[i] = run; if (cursor) cursor[i] = run; run += deg[i]; }
    if (t == 1023) rowptr[n] = run;
}

// fill: inverse slot maps only
__global__ void k_fill(const int* __restrict__ edges, int E,
                       int* __restrict__ cur_s, int* __restrict__ cur_r,
                       int* __restrict__ sm_s, int* __restrict__ sm_r) {
    int e = blockIdx.x * 256 + threadIdx.x;
    if (e < E) {
        int r = edges[e], c = edges[E + e];
        sm_s[e] = atomicAdd(&cur_s[r], 1);
        sm_r[e] = atomicAdd(&cur_r[c], 1);
    }
}

// ---------------- node projections (MFMA): PQK=[nf@W1q | nf@W1k], PV=nf@W3k (bf16)
__global__ __launch_bounds__(512) void k_nodepre2(const float* __restrict__ nf, int n,
                                                  const uint4* __restrict__ pw,
                                                  unsigned short* __restrict__ PQK,
                                                  unsigned short* __restrict__ PVh) {
    __shared__ uint4 xs[32 * 64];   // 32KB, A-frags: [kt4][rtile8][lane64]
    int t = threadIdx.x, lane = t & 63, w = t >> 6;
    int wr = w >> 2, wc = w & 3, l15 = lane & 15, lg = lane >> 4;
    int base = blockIdx.x * 128;
#pragma unroll
    for (int it = 0; it < 4; ++it) {
        int chunk = t + it * 512;
        int row = chunk >> 4, k8 = chunk & 15, k = k8 * 8;
        int node = base + row;
        f32x4 v0 = (f32x4)(0.f), v1 = (f32x4)(0.f);
        if (node < n) {
            const f32x4* s4 = (const f32x4*)(nf + (size_t)node * 128 + k);
            v0 = ntl(s4); v1 = ntl(s4 + 1);
        }
        uint4 pkv;
        pkv.x = pk2(v0.x, v0.y); pkv.y = pk2(v0.z, v0.w);
        pkv.z = pk2(v1.x, v1.y); pkv.w = pk2(v1.z, v1.w);
        int kt = k >> 5, g = (k >> 3) & 3;
        xs[(kt * 8 + (row >> 4)) * 64 + g * 16 + (row & 15)] = pkv;
    }
    __syncthreads();
    f32x4 acc[4][6];
#pragma unroll
    for (int rt = 0; rt < 4; ++rt)
#pragma unroll
        for (int ct = 0; ct < 6; ++ct) acc[rt][ct] = (f32x4)(0.f);
    for (int kt = 0; kt < 4; ++kt) {
        U4B a[4];
#pragma unroll
        for (int rt = 0; rt < 4; ++rt) a[rt].u = xs[(kt * 8 + wr * 4 + rt) * 64 + lane];
        U4B b[6];
#pragma unroll
        for (int ct = 0; ct < 6; ++ct) {
            int nt = wc * 6 + ct;
            int mat = nt >> 3, ntm = nt & 7;
            b[ct].u = pw[(size_t)(FN + mat * 32 + kt * 8 + ntm) * 64 + lane];
        }
#pragma unroll
        for (int rt = 0; rt < 4; ++rt)
#pragma unroll
            for (int ct = 0; ct < 6; ++ct)
                acc[rt][ct] = __builtin_amdgcn_mfma_f32_16x16x32_bf16(a[rt].v, b[ct].v, acc[rt][ct], 0, 0, 0);
    }
#pragma unroll
    for (int rt = 0; rt < 4; ++rt)
#pragma unroll
        for (int ct = 0; ct < 6; ++ct) {
            int nt = wc * 6 + ct;
#pragma unroll
            for (int reg = 0; reg < 4; ++reg) {
                int node = base + (wr * 4 + rt) * 16 + lg * 4 + reg;
                if (node < n) {
                    unsigned short hv = f2bf(acc[rt][ct][reg]);
                    if (nt < 16) PQK[(size_t)node * 256 + nt * 16 + l15] = hv;
                    else         PVh[(size_t)node * 128 + (nt - 16) * 16 + l15] = hv;
                }
            }
        }
}

// ---------------- edge projection (MFMA, 2 rt-passes @32 AGPR) + logits/exp;
// V = (EV+b3)+PV[other] to both slot orders. LDS 48KB: xs16 | ldsE16 | ldsV16.
// edata/evdata rows XOR-swizzled: byte ^= (e_loc&7)<<4
__global__ __launch_bounds__(256) void k_eproj1(const int* __restrict__ edges,
                                                const float* __restrict__ ea, int E,
                                                const uint4* __restrict__ pw,
                                                const unsigned short* __restrict__ PQK,
                                                const unsigned short* __restrict__ PVh,
                                                const float* __restrict__ b1,
                                                const float* __restrict__ w2,
                                                const float* __restrict__ b3,
                                                const int* __restrict__ sm_s,
                                                const int* __restrict__ sm_r,
                                                unsigned short* __restrict__ Vs,
                                                unsigned short* __restrict__ Vr,
                                                float* __restrict__ ess2, float* __restrict__ ers2) {
    __shared__ char lds[49152];
    uint4* xs = (uint4*)lds;          // 16KB A-frags (live through both passes)
    char* ldsE = lds + 16384;         // E3 + b1 rows
    char* ldsV = lds + 32768;         // EV + b3 rows
    int t = threadIdx.x, lane = t & 63, w = t >> 6;
    int wc = w, l15 = lane & 15, lg = lane >> 4;
    int base = blockIdx.x * 64;
#pragma unroll
    for (int it = 0; it < 4; ++it) {
        int chunk = t + it * 256;
        int row = chunk >> 4, k8 = chunk & 15, k = k8 * 8;
        int e = base + row;
        f32x4 v0 = (f32x4)(0.f), v1 = (f32x4)(0.f);
        if (e < E) {
            const f32x4* s4 = (const f32x4*)(ea + (size_t)e * 128 + k);
            v0 = ntl(s4); v1 = ntl(s4 + 1);
        }
        uint4 pkv;
        pkv.x = pk2(v0.x, v0.y); pkv.y = pk2(v0.z, v0.w);
        pkv.z = pk2(v1.x, v1.y); pkv.w = pk2(v1.z, v1.w);
        int kt = k >> 5, g = (k >> 3) & 3;
        xs[(kt * 4 + (row >> 4)) * 64 + g * 16 + (row & 15)] = pkv;
    }
    __syncthreads();
    // two passes over row-halves: acc[2][4] = 32 AGPR instead of 64
#pragma unroll
    for (int pass = 0; pass < 2; ++pass) {
        f32x4 acc[2][4];   // [rt2][ct]: ct 0,1 = E3 cols, ct 2,3 = EV cols
#pragma unroll
        for (int rt2 = 0; rt2 < 2; ++rt2)
#pragma unroll
            for (int ct = 0; ct < 4; ++ct) acc[rt2][ct] = (f32x4)(0.f);
        for (int kt = 0; kt < 4; ++kt) {
            U4B a[2];
#pragma unroll
            for (int rt2 = 0; rt2 < 2; ++rt2)
                a[rt2].u = xs[(kt * 4 + pass * 2 + rt2) * 64 + lane];
            U4B b[4];
            b[0].u = pw[(size_t)(FE3 + kt * 8 + wc * 2 + 0) * 64 + lane];
            b[1].u = pw[(size_t)(FE3 + kt * 8 + wc * 2 + 1) * 64 + lane];
            b[2].u = pw[(size_t)(FEV + kt * 8 + wc * 2 + 0) * 64 + lane];
            b[3].u = pw[(size_t)(FEV + kt * 8 + wc * 2 + 1) * 64 + lane];
#pragma unroll
            for (int rt2 = 0; rt2 < 2; ++rt2)
#pragma unroll
                for (int ct = 0; ct < 4; ++ct)
                    acc[rt2][ct] = __builtin_amdgcn_mfma_f32_16x16x32_bf16(a[rt2].v, b[ct].v, acc[rt2][ct], 0, 0, 0);
        }
        // E3+b1 -> ldsE, EV+b3 -> ldsV; swizzled rows (disjoint rows per pass)
#pragma unroll
        for (int rt2 = 0; rt2 < 2; ++rt2)
#pragma unroll
            for (int cc = 0; cc < 2; ++cc) {
                int col = (wc * 2 + cc) * 16 + l15;
                float b1c = b1[col], b3c = b3[col];
#pragma unroll
                for (int reg = 0; reg < 4; ++reg) {
                    int e_loc = (pass * 2 + rt2) * 16 + lg * 4 + reg;
                    int off = (e_loc * 256 + col * 2) ^ ((e_loc & 7) << 4);
                    *(unsigned short*)(ldsE + off) = f2bf(acc[rt2][cc][reg] + b1c);
                    *(unsigned short*)(ldsV + off) = f2bf(acc[rt2][2 + cc][reg] + b3c);
                }
            }
    }
    __syncthreads();
    // scatter V = (EV+b3) + PV[other] to both slot orders (256B rows, 16 lanes x 16B)
    {
        int e4 = lane >> 4, piece = lane & 15;
#pragma unroll
        for (int i = 0; i < 4; ++i) {
            int e_loc = w * 16 + i * 4 + e4;
            int e = base + e_loc;
            if (e < E) {
                int r = edges[e], c = edges[E + e];
                int off = (e_loc * 256 + piece * 16) ^ ((e_loc & 7) << 4);
                u32x4 vev = *(const u32x4*)(ldsV + off);
                u32x4 pvc = *(const u32x4*)(PVh + (size_t)c * 128 + piece * 8);
                u32x4 pvr = *(const u32x4*)(PVh + (size_t)r * 128 + piece * 8);
                u32x4 vs, vr;
#pragma unroll
                for (int q = 0; q < 4; ++q) {
                    float e0 = lo16(vev[q]);
                    float e1 = hi16(vev[q]);
                    vs[q] = pk2(e0 + lo16(pvc[q]), e1 + hi16(pvc[q]));
                    vr[q] = pk2(e0 + lo16(pvr[q]), e1 + hi16(pvr[q]));
                }
                __builtin_nontemporal_store(vs, (u32x4*)(Vs + (size_t)sm_s[e] * 128 + piece * 8));
                __builtin_nontemporal_store(vr, (u32x4*)(Vr + (size_t)sm_r[e] * 128 + piece * 8));
            }
        }
    }
    int esub = lane >> 3, dg = lane & 7;
    float w2r[16];
    {
        const float4* w4 = (const float4*)(w2 + (dg >> 2) * 64 + (dg & 3) * 16);
#pragma unroll
        for (int q = 0; q < 4; ++q) {
            float4 wv = w4[q];
            w2r[q * 4 + 0] = wv.x; w2r[q * 4 + 1] = wv.y; w2r[q * 4 + 2] = wv.z; w2r[q * 4 + 3] = wv.w;
        }
    }
#pragma unroll
    for (int it = 0; it < 2; ++it) {
        int e_loc = w * 16 + it * 8 + esub;
        int e = base + e_loc;
        if (e >= E) break;
        int r = edges[e], c = edges[E + e];
        const uint4* Aqr = (const uint4*)(PQK + ((size_t)r << 8) + dg * 16);
        const uint4* Akc = (const uint4*)(PQK + ((size_t)c << 8) + 128 + dg * 16);
        const uint4* Aqc = (const uint4*)(PQK + ((size_t)c << 8) + dg * 16);
        const uint4* Akr = (const uint4*)(PQK + ((size_t)r << 8) + 128 + dg * 16);
        float ps = 0.f, pr = 0.f;
#pragma unroll
        for (int half = 0; half < 2; ++half) {
            int off3 = (e_loc * 256 + dg * 32 + half * 16) ^ ((e_loc & 7) << 4);
            uint4 ue3 = *(const uint4*)(ldsE + off3);
            uint4 uqr = Aqr[half], ukc = Akc[half], uqc = Aqc[half], ukr = Akr[half];
            unsigned wqr[4] = {uqr.x, uqr.y, uqr.z, uqr.w};
            unsigned wkc[4] = {ukc.x, ukc.y, ukc.z, ukc.w};
            unsigned wqc[4] = {uqc.x, uqc.y, uqc.z, uqc.w};
            unsigned wkr[4] = {ukr.x, ukr.y, ukr.z, ukr.w};
            unsigned we3[4] = {ue3.x, ue3.y, ue3.z, ue3.w};
#pragma unroll
            for (int q = 0; q < 4; ++q) {
#pragma unroll
                for (int hl = 0; hl < 2; ++hl) {
                    int i = half * 8 + q * 2 + hl;
                    float fqr = hl ? hi16(wqr[q]) : lo16(wqr[q]);
                    float fkc = hl ? hi16(wkc[q]) : lo16(wkc[q]);
                    float fqc = hl ? hi16(wqc[q]) : lo16(wqc[q]);
                    float fkr = hl ? hi16(wkr[q]) : lo16(wkr[q]);
                    float com = hl ? hi16(we3[q]) : lo16(we3[q]);   // e3 + b1 prefolded
                    float hs = fqr + fkc + com; hs = hs > 0.f ? hs : 0.2f * hs;
                    float hr = fqc + fkr + com; hr = hr > 0.f ? hr : 0.2f * hr;
                    ps += hs * w2r[i]; pr += hr * w2r[i];
                }
            }
        }
        ps += __shfl_xor(ps, 1); ps += __shfl_xor(ps, 2);
        pr += __shfl_xor(pr, 1); pr += __shfl_xor(pr, 2);
        float Es = expf(ps), Er = expf(pr);
        if (dg == 0) {
            __builtin_nontemporal_store(Es, &ess2[(size_t)sm_s[e] * 2]);
            __builtin_nontemporal_store(Er, &ers2[(size_t)sm_r[e] * 2]);
        } else if (dg == 4) {
            __builtin_nontemporal_store(Es, &ess2[(size_t)sm_s[e] * 2 + 1]);
            __builtin_nontemporal_store(Er, &ers2[(size_t)sm_r[e] * 2 + 1]);
        }
    }
}

// ---------------- per-node aggregate: fully slot-sequential streaming ----
__global__ __launch_bounds__(256) void k_aggr(int n,
                                              const int* __restrict__ rps, const int* __restrict__ rpr,
                                              const float* __restrict__ ess2, const float* __restrict__ ers2,
                                              const unsigned short* __restrict__ Vs,
                                              const unsigned short* __restrict__ Vr,
                                              unsigned short* __restrict__ out_sh,
                                              unsigned short* __restrict__ out_rh) {
    int w = threadIdx.x >> 6, lane = threadIdx.x & 63;
    int unit = blockIdx.x * 4 + w;
    if (unit >= 2 * n) return;
    bool sent = unit < n;
    int node = sent ? unit : unit - n;
    const int*      rp = sent ? rps : rpr;
    const float*    ex = sent ? ess2 : ers2;
    const unsigned* V  = (const unsigned*)(sent ? Vs : Vr);
    int s0 = rp[node], s1 = rp[node + 1];
    float z0 = 0.f, z1 = 0.f, acca = 0.f, accb = 0.f;
    int j = s0;
    for (; j + 4 <= s1; j += 4) {
        f32x2 ez[4]; unsigned v[4];
#pragma unroll
        for (int q = 0; q < 4; ++q) ez[q] = ntl((const f32x2*)(ex + 2 * (j + q)));
#pragma unroll
        for (int q = 0; q < 4; ++q) v[q] = ntl(V + (size_t)(j + q) * 64 + lane);
#pragma unroll
        for (int q = 0; q < 4; ++q) {
            z0 += ez[q].x; z1 += ez[q].y;
            float aw = (lane < 32) ? ez[q].x : ez[q].y;
            acca += aw * lo16(v[q]); accb += aw * hi16(v[q]);
        }
    }
    for (; j < s1; ++j) {
        f32x2 ez = ntl((const f32x2*)(ex + 2 * j));
        unsigned v = ntl(V + (size_t)j * 64 + lane);
        z0 += ez.x; z1 += ez.y;
        float aw = (lane < 32) ? ez.x : ez.y;
        acca += aw * lo16(v); accb += aw * hi16(v);
    }
    float zz = (lane < 32) ? z0 : z1;
    float rz = 1.f / (zz + 1e-16f);
    unsigned o = pk2(acca * rz, accb * rz);
    unsigned* outp = (unsigned*)(sent ? out_sh : out_rh);
    outp[(size_t)node * 64 + lane] = o;
}

// ---------------- fused MFMA MLP v13: 32-row tile, 8 waves, B direct from L2,
// ZERO barriers in K-loop (hx read-only; B wave-private). LDS 33KB -> high TLP.
__global__ __launch_bounds__(512, 4) void k_mlp13(
    const float* __restrict__ nf, const unsigned short* __restrict__ out_sh,
    const unsigned short* __restrict__ out_rh,
    const float* __restrict__ u, const int* __restrict__ gid, int n,
    const uint4* __restrict__ pw,
    const float* __restrict__ mb0, const float* __restrict__ ls0, const float* __restrict__ lb0,
    const float* __restrict__ mb1, const float* __restrict__ ls1, const float* __restrict__ lb1,
    const float* __restrict__ mb2, float* __restrict__ out) {
    extern __shared__ char smem[];
    char* hx = smem;                           // 32 KB
    float2* red = (float2*)(smem + 32768);     // [32][4]

    int t = threadIdx.x, lane = t & 63, w = t >> 6;   // 8 waves: 2 row x 4 col
    int wr = w >> 2, wc = w & 3, l15 = lane & 15, lg = lane >> 4;
    int base = blockIdx.x * 32;

    // ---- stage X = [nf | sent | recv | u[gid]] into swizzled row-major bf16 ----
#pragma unroll
    for (int it = 0; it < 8; ++it) {
        int chunk = t + it * 512;
        int row = chunk >> 7, kq = chunk & 127;
        int k = kq * 4;
        int node = base + row;
        u32x2 p = (u32x2)(0u);
        if (node < n) {
            int kk = k & 127;
            if (k < 128) {
                f32x4 v = ntl((const f32x4*)(nf + (size_t)node * 128 + kk));
                p.x = pk2(v.x, v.y); p.y = pk2(v.z, v.w);
            } else if (k < 384) {
                const unsigned short* s = (k < 256 ? out_sh : out_rh) + (size_t)node * 128 + kk;
                p = ntl((const u32x2*)s);
            } else {
                f32x4 v = *(const f32x4*)(u + (size_t)gid[node] * 128 + kk);
                p.x = pk2(v.x, v.y); p.y = pk2(v.z, v.w);
            }
        }
        int addr = (row * 1024 + k * 2) ^ ((row & 7) << 4);
        *(u32x2*)(hx + addr) = p;
    }
    __syncthreads();

    f32x4 acc[8];
    // ===== layers 0 and 1 (N=512, LN + ReLU) =====
#pragma unroll
    for (int layer = 0; layer < 2; ++layer) {
        const float* MB = layer ? mb1 : mb0;
        const float* LS = layer ? ls1 : ls0;
        const float* LB = layer ? lb1 : lb0;
        const uint4* PW = pw + ((size_t)(layer ? 512 : 0) + wc * 8) * 64 + lane;
#pragma unroll
        for (int ct = 0; ct < 8; ++ct) acc[ct] = (f32x4)(0.f);

        // barrier-free K-loop: hx read-only, B wave-private from L2
        for (int kt = 0; kt < 16; ++kt) {
            U4B a;
            {
                int row = wr * 16 + l15;
                int addr = (row * 1024 + kt * 64 + lg * 16) ^ ((row & 7) << 4);
                a.u = *(const uint4*)(hx + addr);
            }
#pragma unroll
            for (int h = 0; h < 2; ++h) {
                U4B b[4];
#pragma unroll
                for (int ct = 0; ct < 4; ++ct)
                    b[ct].u = PW[(size_t)(kt * 32 + h * 4 + ct) * 64];
#pragma unroll
                for (int ct = 0; ct < 4; ++ct)
                    acc[h * 4 + ct] = __builtin_amdgcn_mfma_f32_16x16x32_bf16(
                        a.v, b[ct].v, acc[h * 4 + ct], 0, 0, 0);
            }
        }

        float mbv[8], lsv[8], lbv[8];
#pragma unroll
        for (int ct = 0; ct < 8; ++ct) {
            int col = wc * 128 + ct * 16 + l15;
            mbv[ct] = MB[col]; lsv[ct] = LS[col]; lbv[ct] = LB[col];
        }
        // bias + per-row partial sums -> red
#pragma unroll
        for (int reg = 0; reg < 4; ++reg) {
            float p = 0.f, q = 0.f;
#pragma unroll
            for (int ct = 0; ct < 8; ++ct) {
                float y = acc[ct][reg] + mbv[ct];
                acc[ct][reg] = y;
                p += y; q += y * y;
            }
#pragma unroll
            for (int d = 1; d < 16; d <<= 1) { p += __shfl_xor(p, d); q += __shfl_xor(q, d); }
            if (l15 == 0) {
                int row = wr * 16 + lg * 4 + reg;
                red[row * 4 + wc] = make_float2(p, q);
            }
        }
        __syncthreads();   // red complete + all hx reads done (before overwrite)
        // LN + ReLU, write H back swizzled
#pragma unroll
        for (int reg = 0; reg < 4; ++reg) {
            int row = wr * 16 + lg * 4 + reg;
            float2 r0 = red[row * 4 + 0], r1 = red[row * 4 + 1];
            float2 r2 = red[row * 4 + 2], r3 = red[row * 4 + 3];
            float S = r0.x + r1.x + r2.x + r3.x;
            float S2 = r0.y + r1.y + r2.y + r3.y;
            float mu = S * (1.f / 512.f);
            float var = S2 * (1.f / 512.f) - mu * mu;
            float rs = rsqrtf(var + 1e-5f);
            int rswz = (row & 7) << 4;
#pragma unroll
            for (int ct = 0; ct < 8; ++ct) {
                float h = (acc[ct][reg] - mu) * rs * lsv[ct] + lbv[ct];
                h = fmaxf(h, 0.f);
                int col = wc * 128 + ct * 16 + l15;
                int addr = (row * 1024 + col * 2) ^ rswz;
                *(unsigned short*)(hx + addr) = f2bf(h);
            }
        }
        __syncthreads();   // H complete before next layer's reads
    }

    // ===== layer 2 (N=128, bias only); barrier-free =====
    f32x4 a2[2];
#pragma unroll
    for (int ct = 0; ct < 2; ++ct) a2[ct] = (f32x4)(0.f);
    {
        const uint4* PW2 = pw + ((size_t)1024 + wc * 2) * 64 + lane;
        for (int kt = 0; kt < 16; ++kt) {
            U4B a, b[2];
            {
                int row = wr * 16 + l15;
                int addr = (row * 1024 + kt * 64 + lg * 16) ^ ((row & 7) << 4);
                a.u = *(const uint4*)(hx + addr);
            }
#pragma unroll
            for (int ct = 0; ct < 2; ++ct)
                b[ct].u = PW2[(size_t)(kt * 8 + ct) * 64];
#pragma unroll
            for (int ct = 0; ct < 2; ++ct)
                a2[ct] = __builtin_amdgcn_mfma_f32_16x16x32_bf16(a.v, b[ct].v, a2[ct], 0, 0, 0);
        }
    }
    float mb2v[2];
#pragma unroll
    for (int ct = 0; ct < 2; ++ct) mb2v[ct] = mb2[wc * 32 + ct * 16 + l15];
#pragma unroll
    for (int reg = 0; reg < 4; ++reg) {
        int node = base + wr * 16 + lg * 4 + reg;
        if (node < n) {
#pragma unroll
            for (int ct = 0; ct < 2; ++ct)
                __builtin_nontemporal_store(a2[ct][reg] + mb2v[ct],
                    &out[(size_t)node * 128 + wc * 32 + ct * 16 + l15]);
        }
    }
}

extern "C" void kernel_launch(void* const* d_in, const int* in_sizes, int n_in,
                              void* d_out, int out_size, void* d_ws, size_t ws_size,
                              hipStream_t stream) {
    const int*   edges     = (const int*)d_in[0];
    const float* nf        = (const float*)d_in[1];
    const float* ea        = (const float*)d_in[2];
    const float* u         = (const float*)d_in[3];
    const int*   num_nodes = (const int*)d_in[4];
    const float* w1  = (const float*)d_in[5];
    const float* b1  = (const float*)d_in[6];
    const float* w2  = (const float*)d_in[7];
    const float* w3  = (const float*)d_in[8];
    const float* b3  = (const float*)d_in[9];
    const float* mw0 = (const float*)d_in[10];
    const float* mb0 = (const float*)d_in[11];
    const float* ls0 = (const float*)d_in[12];
    const float* lb0 = (const float*)d_in[13];
    const float* mw1 = (const float*)d_in[14];
    const float* mb1 = (const float*)d_in[15];
    const float* ls1 = (const float*)d_in[16];
    const float* lb1 = (const float*)d_in[17];
    const float* mw2 = (const float*)d_in[18];
    const float* mb2 = (const float*)d_in[19];

    int E = in_sizes[0] / 2;
    int n = in_sizes[1] / LATENT;
    int G = in_sizes[4];
    float* out = (float*)d_out;

    char* wsb = (char*)d_ws;
    size_t off = 0;
    auto alloc = [&](size_t bytes) { void* p = (void*)(wsb + off); off += (bytes + 15) & ~(size_t)15; return p; };
    uint4*          pw     = (uint4*)alloc((size_t)1312 * 64 * 16);
    unsigned short* PQK    = (unsigned short*)alloc((size_t)n * 256 * 2);
    unsigned short* PVh    = (unsigned short*)alloc((size_t)n * 128 * 2);
    unsigned short* Vs     = (unsigned short*)alloc((size_t)E * 128 * 2);
    unsigned short* Vr     = (unsigned short*)alloc((size_t)E * 128 * 2);
    float*          ess2   = (float*)alloc((size_t)E * 2 * 4);
    float*          ers2   = (float*)alloc((size_t)E * 2 * 4);
    unsigned short* out_sh = (unsigned short*)alloc((size_t)n * 128 * 2);
    unsigned short* out_rh = (unsigned short*)alloc((size_t)n * 128 * 2);
    int*            gid    = (int*)alloc((size_t)n * 4);
    int*            deg_s  = (int*)alloc((size_t)n * 4);   // zero region (deg_s, deg_r contiguous)
    int*            deg_r  = (int*)alloc((size_t)n * 4);
    int*            cur_s  = (int*)alloc((size_t)n * 4);
    int*            cur_r  = (int*)alloc((size_t)n * 4);
    int*            rps    = (int*)alloc((size_t)(n + 1) * 4);
    int*            rpr    = (int*)alloc((size_t)(n + 1) * 4);
    int*            sm_s   = (int*)alloc((size_t)E * 4);
    int*            sm_r   = (int*)alloc((size_t)E * 4);
    int*            goff   = (int*)alloc((size_t)(G + 1) * 4);
    int*            gcur   = (int*)alloc((size_t)(G + 1) * 4);

    hipMemsetAsync(deg_s, 0, (size_t)2 * n * 4 + 16, stream);

    hipFuncSetAttribute((const void*)k_mlp13, hipFuncAttributeMaxDynamicSharedMemorySize, 33792);

    k_scan<<<1, 1024, 0, stream>>>(num_nodes, G, goff, gcur);
    k_gidfill<<<(n + 255) / 256, 256, 0, stream>>>(goff, G, n, gid);
    k_pack2<<<(1312 * 64 + 255) / 256, 256, 0, stream>>>(mw0, mw1, mw2, w1, w3, pw);
    k_count<<<(E + 255) / 256, 256, 0, stream>>>(edges, E, deg_s, deg_r);
    k_scan<<<1, 1024, 0, stream>>>(deg_s, n, rps, cur_s);
    k_scan<<<1, 1024, 0, stream>>>(deg_r, n, rpr, cur_r);
    k_fill<<<(E + 255) / 256, 256, 0, stream>>>(edges, E, cur_s, cur_r, sm_s, sm_r);
    k_nodepre2<<<(n + 127) / 128, 512, 0, stream>>>(nf, n, pw, PQK, PVh);
    k_eproj1<<<(E + 63) / 64, 256, 0, stream>>>(edges, ea, E, pw, PQK, PVh, b1, w2, b3,
                                                sm_s, sm_r, Vs, Vr, ess2, ers2);
    k_aggr<<<(2 * n + 3) / 4, 256, 0, stream>>>(n, rps, rpr, ess2, ers2, Vs, Vr, out_sh, out_rh);
    k_mlp13<<<(n + 31) / 32, 512, 33792, stream>>>(nf, out_sh, out_rh, u, gid, n, pw,
                                                   mb0, ls0, lb0, mb1, ls1, lb1, mb2, out);
}